// Round 1
// baseline (5038.652 us; speedup 1.0000x reference)
//
#include <hip/hip_runtime.h>

constexpr int BLK = 256;

// ---------------------------------------------------------------- index setup
__global__ void k_detect(const int* __restrict__ ei, int e, int* __restrict__ flag) {
    if (blockIdx.x == 0 && threadIdx.x == 0) {
        // int64 indices < 2^31 -> every odd int32 word is 0
        int is64 = 1;
        for (int i = 0; i < 16; ++i)
            if (ei[2 * i + 1] != 0) { is64 = 0; break; }
        *flag = is64;
    }
}

__global__ void k_cvt_idx(const void* __restrict__ ei, int e, const int* __restrict__ flag,
                          int* __restrict__ rows, int* __restrict__ cols) {
    long i = (long)blockIdx.x * BLK + threadIdx.x;
    if (i >= e) return;
    if (*flag) {
        const long long* p = (const long long*)ei;
        rows[i] = (int)p[i];
        cols[i] = (int)p[(size_t)e + i];
    } else {
        const int* p = (const int*)ei;
        rows[i] = p[i];
        cols[i] = p[(size_t)e + i];
    }
}

// ---------------------------------------------------------------- gcn_norm
__global__ void k_set1(float* __restrict__ p, int n) {
    long i = (long)blockIdx.x * BLK + threadIdx.x;
    if (i < n) p[i] = 1.0f;   // self-loop weight
}

__global__ void k_deg_accum(const int* __restrict__ cols, const float* __restrict__ w,
                            float* __restrict__ deg, int e) {
    long i = (long)blockIdx.x * BLK + threadIdx.x;
    if (i < e) atomicAdd(&deg[cols[i]], w[i]);
}

__global__ void k_rsqrt(float* __restrict__ p, int n) {
    long i = (long)blockIdx.x * BLK + threadIdx.x;
    if (i < n) p[i] = rsqrtf(p[i]);   // deg >= 1 always (self-loop + nonneg weights)
}

__global__ void k_wnorm(const int* __restrict__ rows, const int* __restrict__ cols,
                        const float* __restrict__ w, const float* __restrict__ dinv,
                        float* __restrict__ wn, int e) {
    long i = (long)blockIdx.x * BLK + threadIdx.x;
    if (i < e) wn[i] = dinv[rows[i]] * w[i] * dinv[cols[i]];
}

// ---------------------------------------------------------------- dense GEMM (f32 VALU)
// Each thread: RPT rows x 4 outputs. W tile staged in LDS.
template <int KIN, int KOUT, int CTILE, int RPT, bool RELU_IN>
__global__ __launch_bounds__(256) void k_gemm(const float* __restrict__ X,
                                              const float* __restrict__ W,
                                              float* __restrict__ H, int nrows) {
    constexpr int TPR  = KOUT / 4;        // threads per row (output groups of 4)
    constexpr int QG   = 256 / TPR;       // row groups per block
    constexpr int ROWS = QG * RPT;        // rows per block
    __shared__ float Ws[CTILE * KOUT];

    const int g = threadIdx.x & (TPR - 1);
    const int q = threadIdx.x / TPR;
    const long rbase = (long)blockIdx.x * ROWS + (long)q * RPT;

    float acc[RPT][4];
#pragma unroll
    for (int j = 0; j < RPT; ++j) { acc[j][0] = acc[j][1] = acc[j][2] = acc[j][3] = 0.f; }

    for (int c0 = 0; c0 < KIN; c0 += CTILE) {
        __syncthreads();
#pragma unroll
        for (int i = threadIdx.x; i < CTILE * KOUT / 4; i += 256)
            ((float4*)Ws)[i] = ((const float4*)(W + (size_t)c0 * KOUT))[i];
        __syncthreads();

#pragma unroll 4
        for (int c = 0; c < CTILE; c += 4) {
            float4 xv[RPT];
#pragma unroll
            for (int j = 0; j < RPT; ++j) {
                long r = rbase + j;
                if (r < nrows) {
                    xv[j] = *(const float4*)(X + (size_t)r * KIN + c0 + c);
                    if (RELU_IN) {
                        xv[j].x = fmaxf(xv[j].x, 0.f);
                        xv[j].y = fmaxf(xv[j].y, 0.f);
                        xv[j].z = fmaxf(xv[j].z, 0.f);
                        xv[j].w = fmaxf(xv[j].w, 0.f);
                    }
                } else {
                    xv[j] = float4{0.f, 0.f, 0.f, 0.f};
                }
            }
#pragma unroll
            for (int cc = 0; cc < 4; ++cc) {
                const float4 w4 = *(const float4*)(&Ws[(c + cc) * KOUT + 4 * g]);
#pragma unroll
                for (int j = 0; j < RPT; ++j) {
                    const float xs = (&xv[j].x)[cc];  // cc is compile-time (unrolled)
                    acc[j][0] = fmaf(xs, w4.x, acc[j][0]);
                    acc[j][1] = fmaf(xs, w4.y, acc[j][1]);
                    acc[j][2] = fmaf(xs, w4.z, acc[j][2]);
                    acc[j][3] = fmaf(xs, w4.w, acc[j][3]);
                }
            }
        }
    }
#pragma unroll
    for (int j = 0; j < RPT; ++j) {
        long r = rbase + j;
        if (r < nrows) {
            float4 o{acc[j][0], acc[j][1], acc[j][2], acc[j][3]};
            *(float4*)(H + (size_t)r * KOUT + 4 * g) = o;
        }
    }
}

// ---------------------------------------------------------------- propagation
// hp[n] = b + dinv[n]^2 * h[n]   (bias + self-loop term; also zero-inits accumulator)
template <int K>
__global__ void k_prop_init(const float* __restrict__ h, const float* __restrict__ dinv,
                            const float* __restrict__ b, float* __restrict__ hp, int n) {
    constexpr int CH = K / 4;
    long i = (long)blockIdx.x * BLK + threadIdx.x;
    if (i >= (long)n * CH) return;
    int node = (int)(i / CH);
    int ch   = (int)(i % CH);
    float di = dinv[node];
    float s  = di * di;
    float4 hv = ((const float4*)h)[i];
    float4 bv = ((const float4*)b)[ch];
    float4 o{fmaf(s, hv.x, bv.x), fmaf(s, hv.y, bv.y), fmaf(s, hv.z, bv.z), fmaf(s, hv.w, bv.w)};
    ((float4*)hp)[i] = o;
}

// hp[col] += wnorm * h[row], 4 channels per thread
template <int K>
__global__ void k_prop_edges(const int* __restrict__ rows, const int* __restrict__ cols,
                             const float* __restrict__ wn, const float* __restrict__ h,
                             float* __restrict__ hp, int e) {
    constexpr int CH = K / 4;
    long i = (long)blockIdx.x * BLK + threadIdx.x;
    if (i >= (long)e * CH) return;
    int eid = (int)(i / CH);
    int c   = (int)(i % CH);
    int r = rows[eid], d = cols[eid];
    float wv = wn[eid];
    const float4 hv = *(const float4*)(h + (size_t)r * K + 4 * c);
    float* dst = hp + (size_t)d * K + 4 * c;
    atomicAdd(dst + 0, wv * hv.x);
    atomicAdd(dst + 1, wv * hv.y);
    atomicAdd(dst + 2, wv * hv.z);
    atomicAdd(dst + 3, wv * hv.w);
}

// ---------------------------------------------------------------- layer 3 (32 -> 1)
__global__ void k_lin3(const float* __restrict__ X, const float* __restrict__ W3,
                       float* __restrict__ h3, int n) {
    long i = (long)blockIdx.x * BLK + threadIdx.x;
    if (i >= n) return;
    const float4* xr = (const float4*)(X + (size_t)i * 32);
    float acc = 0.f;
#pragma unroll
    for (int c = 0; c < 8; ++c) {
        float4 xv = xr[c];
        float4 wv = ((const float4*)W3)[c];
        acc = fmaf(fmaxf(xv.x, 0.f), wv.x, acc);
        acc = fmaf(fmaxf(xv.y, 0.f), wv.y, acc);
        acc = fmaf(fmaxf(xv.z, 0.f), wv.z, acc);
        acc = fmaf(fmaxf(xv.w, 0.f), wv.w, acc);
    }
    h3[i] = acc;
}

__global__ void k_out_init(const float* __restrict__ h3, const float* __restrict__ dinv,
                           const float* __restrict__ b3, float* __restrict__ out, int n) {
    long i = (long)blockIdx.x * BLK + threadIdx.x;
    if (i >= n) return;
    float di = dinv[i];
    out[i] = fmaf(di * di, h3[i], b3[0]);
}

__global__ void k_out_edges(const int* __restrict__ rows, const int* __restrict__ cols,
                            const float* __restrict__ wn, const float* __restrict__ h3,
                            float* __restrict__ out, int e) {
    long i = (long)blockIdx.x * BLK + threadIdx.x;
    if (i >= e) return;
    atomicAdd(&out[cols[i]], wn[i] * h3[rows[i]]);
}

// ---------------------------------------------------------------- launch
extern "C" void kernel_launch(void* const* d_in, const int* in_sizes, int n_in,
                              void* d_out, int out_size, void* d_ws, size_t ws_size,
                              hipStream_t stream) {
    const float* x  = (const float*)d_in[0];
    const void*  ei = d_in[1];
    const float* ew = (const float*)d_in[2];
    const float* W1 = (const float*)d_in[3];
    const float* b1 = (const float*)d_in[4];
    const float* W2 = (const float*)d_in[5];
    const float* b2 = (const float*)d_in[6];
    const float* W3 = (const float*)d_in[7];
    const float* b3 = (const float*)d_in[8];
    float* out = (float*)d_out;

    const int n = in_sizes[0] / 512;
    const int e = in_sizes[2];

    char* ws = (char*)d_ws;
    size_t off = 0;
    auto alloc = [&](size_t bytes) {
        void* p = ws + off;
        off = (off + bytes + 255) & ~(size_t)255;
        return p;
    };
    int*   flag = (int*)  alloc(4);
    int*   rows = (int*)  alloc((size_t)e * 4);
    int*   cols = (int*)  alloc((size_t)e * 4);
    float* dinv = (float*)alloc((size_t)n * 4);
    float* wn   = (float*)alloc((size_t)e * 4);
    float* bufA = (float*)alloc((size_t)n * 64 * 4);
    float* bufB = (float*)alloc((size_t)n * 64 * 4);
    (void)ws_size; (void)n_in; (void)out_size;

    const int gb_e = (e + BLK - 1) / BLK;
    const int gb_n = (n + BLK - 1) / BLK;

    k_detect<<<1, 64, 0, stream>>>((const int*)ei, e, flag);
    k_cvt_idx<<<gb_e, BLK, 0, stream>>>(ei, e, flag, rows, cols);

    k_set1<<<gb_n, BLK, 0, stream>>>(dinv, n);
    k_deg_accum<<<gb_e, BLK, 0, stream>>>(cols, ew, dinv, e);
    k_rsqrt<<<gb_n, BLK, 0, stream>>>(dinv, n);
    k_wnorm<<<gb_e, BLK, 0, stream>>>(rows, cols, ew, dinv, wn, e);

    // ---- layer 1: 512 -> 64
    {
        constexpr int ROWS = (256 / (64 / 4)) * 8;  // 128
        k_gemm<512, 64, 64, 8, false><<<(n + ROWS - 1) / ROWS, BLK, 0, stream>>>(x, W1, bufA, n);
        long t1 = (long)n * 16;
        k_prop_init<64><<<(int)((t1 + BLK - 1) / BLK), BLK, 0, stream>>>(bufA, dinv, b1, bufB, n);
        long t2 = (long)e * 16;
        k_prop_edges<64><<<(int)((t2 + BLK - 1) / BLK), BLK, 0, stream>>>(rows, cols, wn, bufA, bufB, e);
    }
    // ---- layer 2: 64 -> 32 (ReLU on input)
    {
        constexpr int ROWS = (256 / (32 / 4)) * 8;  // 256
        k_gemm<64, 32, 64, 8, true><<<(n + ROWS - 1) / ROWS, BLK, 0, stream>>>(bufB, W2, bufA, n);
        long t1 = (long)n * 8;
        k_prop_init<32><<<(int)((t1 + BLK - 1) / BLK), BLK, 0, stream>>>(bufA, dinv, b2, bufB, n);
        long t2 = (long)e * 8;
        k_prop_edges<32><<<(int)((t2 + BLK - 1) / BLK), BLK, 0, stream>>>(rows, cols, wn, bufA, bufB, e);
    }
    // ---- layer 3: 32 -> 1 (ReLU on input)
    {
        k_lin3<<<gb_n, BLK, 0, stream>>>(bufB, W3, bufA, n);
        k_out_init<<<gb_n, BLK, 0, stream>>>(bufA, dinv, b3, out, n);
        k_out_edges<<<gb_e, BLK, 0, stream>>>(rows, cols, wn, bufA, out, e);
    }
}

// Round 2
// 1381.159 us; speedup vs baseline: 3.6481x; 3.6481x over previous
//
#include <hip/hip_runtime.h>

constexpr int BLK = 256;

// ---------------------------------------------------------------- index setup
__global__ void k_detect(const int* __restrict__ ei, int e, int* __restrict__ flag) {
    if (blockIdx.x == 0 && threadIdx.x == 0) {
        int is64 = 1;
        for (int i = 0; i < 16; ++i)
            if (ei[2 * i + 1] != 0) { is64 = 0; break; }
        *flag = is64;
    }
}

__global__ void k_cvt_idx(const void* __restrict__ ei, int e, const int* __restrict__ flag,
                          int* __restrict__ rows, int* __restrict__ cols) {
    long i = (long)blockIdx.x * BLK + threadIdx.x;
    if (i >= e) return;
    if (*flag) {
        const long long* p = (const long long*)ei;
        rows[i] = (int)p[i];
        cols[i] = (int)p[(size_t)e + i];
    } else {
        const int* p = (const int*)ei;
        rows[i] = p[i];
        cols[i] = p[(size_t)e + i];
    }
}

// ---------------------------------------------------------------- CSR build
__global__ void k_zero_i(int* __restrict__ p, int n) {
    long i = (long)blockIdx.x * BLK + threadIdx.x;
    if (i < n) p[i] = 0;
}

__global__ void k_hist(const int* __restrict__ cols, int* __restrict__ counts, int e) {
    long i = (long)blockIdx.x * BLK + threadIdx.x;
    if (i < e) atomicAdd(&counts[cols[i]], 1);
}

// block-level exclusive scan: 256 threads x 4 items = 1024/block (in-place safe)
__global__ void k_scan1(const int* __restrict__ in, int* __restrict__ out,
                        int* __restrict__ bsum, int n) {
    __shared__ int sh[256];
    const int t = threadIdx.x;
    const int base = blockIdx.x * 1024 + t * 4;
    int v[4];
    int s = 0;
#pragma unroll
    for (int k = 0; k < 4; ++k) {
        int i = base + k;
        v[k] = (i < n) ? in[i] : 0;
        s += v[k];
    }
    sh[t] = s;
    __syncthreads();
    for (int d = 1; d < 256; d <<= 1) {
        int x = (t >= d) ? sh[t - d] : 0;
        __syncthreads();
        sh[t] += x;
        __syncthreads();
    }
    int excl = (t == 0) ? 0 : sh[t - 1];
    if (t == 255) bsum[blockIdx.x] = sh[255];
#pragma unroll
    for (int k = 0; k < 4; ++k) {
        int i = base + k;
        if (i < n) { out[i] = excl; excl += v[k]; }
    }
}

__global__ void k_scan2(int* __restrict__ bsum, int nb) {
    __shared__ int sh[128];
    const int t = threadIdx.x;
    sh[t] = (t < nb) ? bsum[t] : 0;
    __syncthreads();
    for (int d = 1; d < 128; d <<= 1) {
        int x = (t >= d) ? sh[t - d] : 0;
        __syncthreads();
        sh[t] += x;
        __syncthreads();
    }
    if (t < nb) bsum[t] = (t == 0) ? 0 : sh[t - 1];
}

__global__ void k_scan3(int* __restrict__ offs, int* __restrict__ cursor,
                        const int* __restrict__ scanned, const int* __restrict__ bsum,
                        int n, int e) {
    long i = (long)blockIdx.x * BLK + threadIdx.x;
    if (i < n) {
        int v = scanned[i] + bsum[i >> 10];
        offs[i] = v;
        cursor[i] = v;
    }
    if (i == 0) offs[n] = e;
}

// scatter edges into CSR order (by destination); payload packed 8B: (src, weight)
__global__ void k_scatter(const int* __restrict__ rows, const int* __restrict__ cols,
                          const float* __restrict__ ew, int* __restrict__ cursor,
                          int2* __restrict__ csrp, int e) {
    long i = (long)blockIdx.x * BLK + threadIdx.x;
    if (i >= e) return;
    int c = cols[i];
    int p = atomicAdd(&cursor[c], 1);
    csrp[p] = make_int2(rows[i], __float_as_int(ew[i]));
}

// deg[nd] = 1 + sum(w) over incoming edges -> dinv = rsqrt(deg)
__global__ void k_deg(const int* __restrict__ offs, const int2* __restrict__ csrp,
                      float* __restrict__ dinv, int n) {
    long nd = (long)blockIdx.x * BLK + threadIdx.x;
    if (nd >= n) return;
    float s = 1.0f;
    int j1 = offs[nd + 1];
    for (int j = offs[nd]; j < j1; ++j) s += __int_as_float(csrp[j].y);
    dinv[nd] = rsqrtf(s);
}

// fold dinv[src] into the stored weight: w2 = w * dinv[src]
__global__ void k_csrnorm(int2* __restrict__ csrp, const float* __restrict__ dinv, int e) {
    long i = (long)blockIdx.x * BLK + threadIdx.x;
    if (i >= e) return;
    int2 p = csrp[i];
    csrp[i].y = __float_as_int(__int_as_float(p.y) * dinv[p.x]);
}

// ---------------------------------------------------------------- dense GEMM (f32 VALU)
template <int KIN, int KOUT, int CTILE, int RPT, bool RELU_IN>
__global__ __launch_bounds__(256) void k_gemm(const float* __restrict__ X,
                                              const float* __restrict__ W,
                                              float* __restrict__ H, int nrows) {
    constexpr int TPR  = KOUT / 4;
    constexpr int QG   = 256 / TPR;
    constexpr int ROWS = QG * RPT;
    __shared__ float Ws[CTILE * KOUT];

    const int g = threadIdx.x & (TPR - 1);
    const int q = threadIdx.x / TPR;
    const long rbase = (long)blockIdx.x * ROWS + (long)q * RPT;

    float acc[RPT][4];
#pragma unroll
    for (int j = 0; j < RPT; ++j) { acc[j][0] = acc[j][1] = acc[j][2] = acc[j][3] = 0.f; }

    for (int c0 = 0; c0 < KIN; c0 += CTILE) {
        __syncthreads();
#pragma unroll
        for (int i = threadIdx.x; i < CTILE * KOUT / 4; i += 256)
            ((float4*)Ws)[i] = ((const float4*)(W + (size_t)c0 * KOUT))[i];
        __syncthreads();

#pragma unroll 4
        for (int c = 0; c < CTILE; c += 4) {
            float4 xv[RPT];
#pragma unroll
            for (int j = 0; j < RPT; ++j) {
                long r = rbase + j;
                if (r < nrows) {
                    xv[j] = *(const float4*)(X + (size_t)r * KIN + c0 + c);
                    if (RELU_IN) {
                        xv[j].x = fmaxf(xv[j].x, 0.f);
                        xv[j].y = fmaxf(xv[j].y, 0.f);
                        xv[j].z = fmaxf(xv[j].z, 0.f);
                        xv[j].w = fmaxf(xv[j].w, 0.f);
                    }
                } else {
                    xv[j] = float4{0.f, 0.f, 0.f, 0.f};
                }
            }
#pragma unroll
            for (int cc = 0; cc < 4; ++cc) {
                const float4 w4 = *(const float4*)(&Ws[(c + cc) * KOUT + 4 * g]);
#pragma unroll
                for (int j = 0; j < RPT; ++j) {
                    const float xs = (&xv[j].x)[cc];
                    acc[j][0] = fmaf(xs, w4.x, acc[j][0]);
                    acc[j][1] = fmaf(xs, w4.y, acc[j][1]);
                    acc[j][2] = fmaf(xs, w4.z, acc[j][2]);
                    acc[j][3] = fmaf(xs, w4.w, acc[j][3]);
                }
            }
        }
    }
#pragma unroll
    for (int j = 0; j < RPT; ++j) {
        long r = rbase + j;
        if (r < nrows) {
            float4 o{acc[j][0], acc[j][1], acc[j][2], acc[j][3]};
            *(float4*)(H + (size_t)r * KOUT + 4 * g) = o;
        }
    }
}

// ---------------------------------------------------------------- propagation (CSR gather)
// out[nd,ch] = dinv[nd] * sum_j w2_j * h[src_j,ch] + dinv[nd]^2 * h[nd,ch] + b[ch]
template <int K>
__global__ __launch_bounds__(256) void k_prop(const int* __restrict__ offs,
                                              const int2* __restrict__ csrp,
                                              const float* __restrict__ h,
                                              const float* __restrict__ dinv,
                                              const float* __restrict__ bias,
                                              float* __restrict__ out, int n) {
    constexpr int NPB = 256 / K;
    const int t  = threadIdx.x;
    const int ch = t & (K - 1);
    const int ln = t / K;
    const long nd = (long)blockIdx.x * NPB + ln;
    if (nd >= n) return;

    const int j0 = offs[nd], j1 = offs[nd + 1];
    float acc = 0.f;
    int j = j0;
    for (; j + 1 < j1; j += 2) {
        int2 p0 = csrp[j];
        int2 p1 = csrp[j + 1];
        float h0 = h[(size_t)p0.x * K + ch];
        float h1 = h[(size_t)p1.x * K + ch];
        acc = fmaf(__int_as_float(p0.y), h0, acc);
        acc = fmaf(__int_as_float(p1.y), h1, acc);
    }
    if (j < j1) {
        int2 p0 = csrp[j];
        acc = fmaf(__int_as_float(p0.y), h[(size_t)p0.x * K + ch], acc);
    }
    const float di = dinv[nd];
    const float hv = h[(size_t)nd * K + ch];
    out[(size_t)nd * K + ch] = fmaf(di, acc, fmaf(di * di, hv, bias[ch]));
}

// ---------------------------------------------------------------- layer 3 linear (32 -> 1)
__global__ void k_lin3(const float* __restrict__ X, const float* __restrict__ W3,
                       float* __restrict__ h3, int n) {
    long i = (long)blockIdx.x * BLK + threadIdx.x;
    if (i >= n) return;
    const float4* xr = (const float4*)(X + (size_t)i * 32);
    float acc = 0.f;
#pragma unroll
    for (int c = 0; c < 8; ++c) {
        float4 xv = xr[c];
        float4 wv = ((const float4*)W3)[c];
        acc = fmaf(fmaxf(xv.x, 0.f), wv.x, acc);
        acc = fmaf(fmaxf(xv.y, 0.f), wv.y, acc);
        acc = fmaf(fmaxf(xv.z, 0.f), wv.z, acc);
        acc = fmaf(fmaxf(xv.w, 0.f), wv.w, acc);
    }
    h3[i] = acc;
}

// ---------------------------------------------------------------- launch
extern "C" void kernel_launch(void* const* d_in, const int* in_sizes, int n_in,
                              void* d_out, int out_size, void* d_ws, size_t ws_size,
                              hipStream_t stream) {
    const float* x  = (const float*)d_in[0];
    const void*  ei = d_in[1];
    const float* ew = (const float*)d_in[2];
    const float* W1 = (const float*)d_in[3];
    const float* b1 = (const float*)d_in[4];
    const float* W2 = (const float*)d_in[5];
    const float* b2 = (const float*)d_in[6];
    const float* W3 = (const float*)d_in[7];
    const float* b3 = (const float*)d_in[8];
    float* out = (float*)d_out;

    const int n = in_sizes[0] / 512;
    const int e = in_sizes[2];

    char* ws = (char*)d_ws;
    size_t off = 0;
    auto alloc = [&](size_t bytes) {
        void* p = ws + off;
        off = (off + bytes + 255) & ~(size_t)255;
        return p;
    };
    int*   flag    = (int*)  alloc(4);
    int*   rows    = (int*)  alloc((size_t)e * 4);        // } aliased as bufA after scatter
    int*   cols    = (int*)  alloc((size_t)e * 4);        // }
    float* bufA    = (float*)rows;                        // n*64 floats = 25.6MB <= 2*e*4
    int*   counts  = (int*)  alloc((size_t)n * 4);
    int*   offs    = (int*)  alloc((size_t)(n + 1) * 4);
    int*   cursor  = (int*)  alloc((size_t)n * 4);
    int*   bsum    = (int*)  alloc(512);
    int2*  csrp    = (int2*) alloc((size_t)e * 8);
    float* dinv    = (float*)alloc((size_t)n * 4);
    float* bufB    = (float*)alloc((size_t)n * 64 * 4);
    (void)ws_size; (void)n_in; (void)out_size;

    const int gb_e = (e + BLK - 1) / BLK;
    const int gb_n = (n + BLK - 1) / BLK;
    const int nb_scan = (n + 1023) / 1024;

    k_detect<<<1, 64, 0, stream>>>((const int*)ei, e, flag);
    k_cvt_idx<<<gb_e, BLK, 0, stream>>>(ei, e, flag, rows, cols);

    // CSR build (sorted by destination)
    k_zero_i<<<gb_n, BLK, 0, stream>>>(counts, n);
    k_hist<<<gb_e, BLK, 0, stream>>>(cols, counts, e);
    k_scan1<<<nb_scan, 256, 0, stream>>>(counts, counts, bsum, n);
    k_scan2<<<1, 128, 0, stream>>>(bsum, nb_scan);
    k_scan3<<<gb_n, BLK, 0, stream>>>(offs, cursor, counts, bsum, n, e);
    k_scatter<<<gb_e, BLK, 0, stream>>>(rows, cols, ew, cursor, csrp, e);
    k_deg<<<gb_n, BLK, 0, stream>>>(offs, csrp, dinv, n);
    k_csrnorm<<<gb_e, BLK, 0, stream>>>(csrp, dinv, e);

    // ---- layer 1: 512 -> 64   (bufA aliases rows/cols; scatter is done by now)
    {
        constexpr int ROWS = (256 / (64 / 4)) * 8;  // 128
        k_gemm<512, 64, 64, 8, false><<<(n + ROWS - 1) / ROWS, BLK, 0, stream>>>(x, W1, bufA, n);
        k_prop<64><<<(n + 3) / 4, 256, 0, stream>>>(offs, csrp, bufA, dinv, b1, bufB, n);
    }
    // ---- layer 2: 64 -> 32 (ReLU applied on GEMM input)
    {
        constexpr int ROWS = (256 / (32 / 4)) * 8;  // 256
        k_gemm<64, 32, 64, 8, true><<<(n + ROWS - 1) / ROWS, BLK, 0, stream>>>(bufB, W2, bufA, n);
        k_prop<32><<<(n + 7) / 8, 256, 0, stream>>>(offs, csrp, bufA, dinv, b2, bufB, n);
    }
    // ---- layer 3: 32 -> 1 (ReLU applied inside lin3)
    {
        k_lin3<<<gb_n, BLK, 0, stream>>>(bufB, W3, bufA, n);
        k_prop<1><<<(n + 255) / 256, 256, 0, stream>>>(offs, csrp, bufA, dinv, b3, out, n);
    }
}

// Round 3
// 867.071 us; speedup vs baseline: 5.8111x; 1.5929x over previous
//
#include <hip/hip_runtime.h>

constexpr int BLK = 256;

typedef __bf16 bf16x8 __attribute__((ext_vector_type(8)));
typedef float  f32x4  __attribute__((ext_vector_type(4)));

// ---------------------------------------------------------------- index setup
__global__ void k_detect(const int* __restrict__ ei, int e, int* __restrict__ flag) {
    if (blockIdx.x == 0 && threadIdx.x == 0) {
        int is64 = 1;
        for (int i = 0; i < 16; ++i)
            if (ei[2 * i + 1] != 0) { is64 = 0; break; }
        *flag = is64;
    }
}

__global__ void k_cvt_idx(const void* __restrict__ ei, int e, const int* __restrict__ flag,
                          int* __restrict__ rows, int* __restrict__ cols) {
    long i = (long)blockIdx.x * BLK + threadIdx.x;
    if (i >= e) return;
    if (*flag) {
        const long long* p = (const long long*)ei;
        rows[i] = (int)p[i];
        cols[i] = (int)p[(size_t)e + i];
    } else {
        const int* p = (const int*)ei;
        rows[i] = p[i];
        cols[i] = p[(size_t)e + i];
    }
}

// ---------------------------------------------------------------- CSR build
__global__ void k_zero_i(int* __restrict__ p, int n) {
    long i = (long)blockIdx.x * BLK + threadIdx.x;
    if (i < n) p[i] = 0;
}

__global__ void k_hist(const int* __restrict__ cols, int* __restrict__ counts, int e) {
    long i = (long)blockIdx.x * BLK + threadIdx.x;
    if (i < e) atomicAdd(&counts[cols[i]], 1);
}

__global__ void k_scan1(const int* __restrict__ in, int* __restrict__ out,
                        int* __restrict__ bsum, int n) {
    __shared__ int sh[256];
    const int t = threadIdx.x;
    const int base = blockIdx.x * 1024 + t * 4;
    int v[4];
    int s = 0;
#pragma unroll
    for (int k = 0; k < 4; ++k) {
        int i = base + k;
        v[k] = (i < n) ? in[i] : 0;
        s += v[k];
    }
    sh[t] = s;
    __syncthreads();
    for (int d = 1; d < 256; d <<= 1) {
        int x = (t >= d) ? sh[t - d] : 0;
        __syncthreads();
        sh[t] += x;
        __syncthreads();
    }
    int excl = (t == 0) ? 0 : sh[t - 1];
    if (t == 255) bsum[blockIdx.x] = sh[255];
#pragma unroll
    for (int k = 0; k < 4; ++k) {
        int i = base + k;
        if (i < n) { out[i] = excl; excl += v[k]; }
    }
}

__global__ void k_scan2(int* __restrict__ bsum, int nb) {
    __shared__ int sh[128];
    const int t = threadIdx.x;
    sh[t] = (t < nb) ? bsum[t] : 0;
    __syncthreads();
    for (int d = 1; d < 128; d <<= 1) {
        int x = (t >= d) ? sh[t - d] : 0;
        __syncthreads();
        sh[t] += x;
        __syncthreads();
    }
    if (t < nb) bsum[t] = (t == 0) ? 0 : sh[t - 1];
}

__global__ void k_scan3(int* __restrict__ offs, int* __restrict__ cursor,
                        const int* __restrict__ scanned, const int* __restrict__ bsum,
                        int n, int e) {
    long i = (long)blockIdx.x * BLK + threadIdx.x;
    if (i < n) {
        int v = scanned[i] + bsum[i >> 10];
        offs[i] = v;
        cursor[i] = v;
    }
    if (i == 0) offs[n] = e;
}

__global__ void k_scatter(const int* __restrict__ rows, const int* __restrict__ cols,
                          const float* __restrict__ ew, int* __restrict__ cursor,
                          int2* __restrict__ csrp, int e) {
    long i = (long)blockIdx.x * BLK + threadIdx.x;
    if (i >= e) return;
    int c = cols[i];
    int p = atomicAdd(&cursor[c], 1);
    csrp[p] = make_int2(rows[i], __float_as_int(ew[i]));
}

__global__ void k_deg(const int* __restrict__ offs, const int2* __restrict__ csrp,
                      float* __restrict__ dinv, int n) {
    long nd = (long)blockIdx.x * BLK + threadIdx.x;
    if (nd >= n) return;
    float s = 1.0f;
    int j1 = offs[nd + 1];
    for (int j = offs[nd]; j < j1; ++j) s += __int_as_float(csrp[j].y);
    dinv[nd] = rsqrtf(s);
}

__global__ void k_csrnorm(int2* __restrict__ csrp, const float* __restrict__ dinv, int e) {
    long i = (long)blockIdx.x * BLK + threadIdx.x;
    if (i >= e) return;
    int2 p = csrp[i];
    csrp[i].y = __float_as_int(__int_as_float(p.y) * dinv[p.x]);
}

// ---------------------------------------------------------------- W1 -> bf16 transposed [KOUT][KIN]
__global__ void k_wcvt(const float* __restrict__ W, __bf16* __restrict__ Wt,
                       int kin, int kout) {
    int i = blockIdx.x * BLK + threadIdx.x;
    if (i >= kin * kout) return;
    int k = i / kout, nn = i % kout;
    Wt[(size_t)nn * kin + k] = (__bf16)W[i];
}

// ---------------------------------------------------------------- GEMM1: bf16 MFMA, fused f32->bf16
// Block = 4 waves; each wave computes 16 rows x 64 cols. A read directly from
// global X (16-lane cluster = 128B contiguous per row); Wt is L2-resident.
__global__ __launch_bounds__(256) void k_gemm1_mfma(const float* __restrict__ X,
                                                    const __bf16* __restrict__ Wt,
                                                    float* __restrict__ H, int nrows) {
    const int wave = threadIdx.x >> 6;
    const int lane = threadIdx.x & 63;
    const int l15  = lane & 15;
    const int lq   = lane >> 4;                 // 0..3
    const long rbase = (long)blockIdx.x * 64 + wave * 16;

    long arow = rbase + l15;
    if (arow >= nrows) arow = nrows - 1;        // clamp loads; stores guarded
    const float* xr = X + (size_t)arow * 512 + lq * 8;

    f32x4 acc[4] = {{0.f,0.f,0.f,0.f},{0.f,0.f,0.f,0.f},{0.f,0.f,0.f,0.f},{0.f,0.f,0.f,0.f}};

    for (int k0 = 0; k0 < 512; k0 += 32) {
        float4 a0 = *(const float4*)(xr + k0);
        float4 a1 = *(const float4*)(xr + k0 + 4);
        bf16x8 af;
        af[0] = (__bf16)a0.x; af[1] = (__bf16)a0.y; af[2] = (__bf16)a0.z; af[3] = (__bf16)a0.w;
        af[4] = (__bf16)a1.x; af[5] = (__bf16)a1.y; af[6] = (__bf16)a1.z; af[7] = (__bf16)a1.w;
#pragma unroll
        for (int t = 0; t < 4; ++t) {
            // B fragment: col = t*16 + l15, k = k0 + lq*8 .. +7  (Wt row-major [64][512])
            bf16x8 bf_ = *(const bf16x8*)(Wt + (size_t)(t * 16 + l15) * 512 + k0 + lq * 8);
            acc[t] = __builtin_amdgcn_mfma_f32_16x16x32_bf16(af, bf_, acc[t], 0, 0, 0);
        }
    }
    // C layout (verified m89): col = lane&15, row = (lane>>4)*4 + reg
#pragma unroll
    for (int t = 0; t < 4; ++t) {
#pragma unroll
        for (int r = 0; r < 4; ++r) {
            long row = rbase + lq * 4 + r;
            if (row < nrows) H[(size_t)row * 64 + t * 16 + l15] = acc[t][r];
        }
    }
}

// ---------------------------------------------------------------- dense GEMM (f32 VALU) for layer 2
template <int KIN, int KOUT, int CTILE, int RPT, bool RELU_IN>
__global__ __launch_bounds__(256) void k_gemm(const float* __restrict__ X,
                                              const float* __restrict__ W,
                                              float* __restrict__ H, int nrows) {
    constexpr int TPR  = KOUT / 4;
    constexpr int QG   = 256 / TPR;
    constexpr int ROWS = QG * RPT;
    __shared__ float Ws[CTILE * KOUT];

    const int g = threadIdx.x & (TPR - 1);
    const int q = threadIdx.x / TPR;
    const long rbase = (long)blockIdx.x * ROWS + (long)q * RPT;

    float acc[RPT][4];
#pragma unroll
    for (int j = 0; j < RPT; ++j) { acc[j][0] = acc[j][1] = acc[j][2] = acc[j][3] = 0.f; }

    for (int c0 = 0; c0 < KIN; c0 += CTILE) {
        __syncthreads();
#pragma unroll
        for (int i = threadIdx.x; i < CTILE * KOUT / 4; i += 256)
            ((float4*)Ws)[i] = ((const float4*)(W + (size_t)c0 * KOUT))[i];
        __syncthreads();

#pragma unroll 4
        for (int c = 0; c < CTILE; c += 4) {
            float4 xv[RPT];
#pragma unroll
            for (int j = 0; j < RPT; ++j) {
                long r = rbase + j;
                if (r < nrows) {
                    xv[j] = *(const float4*)(X + (size_t)r * KIN + c0 + c);
                    if (RELU_IN) {
                        xv[j].x = fmaxf(xv[j].x, 0.f);
                        xv[j].y = fmaxf(xv[j].y, 0.f);
                        xv[j].z = fmaxf(xv[j].z, 0.f);
                        xv[j].w = fmaxf(xv[j].w, 0.f);
                    }
                } else {
                    xv[j] = float4{0.f, 0.f, 0.f, 0.f};
                }
            }
#pragma unroll
            for (int cc = 0; cc < 4; ++cc) {
                const float4 w4 = *(const float4*)(&Ws[(c + cc) * KOUT + 4 * g]);
#pragma unroll
                for (int j = 0; j < RPT; ++j) {
                    const float xs = (&xv[j].x)[cc];
                    acc[j][0] = fmaf(xs, w4.x, acc[j][0]);
                    acc[j][1] = fmaf(xs, w4.y, acc[j][1]);
                    acc[j][2] = fmaf(xs, w4.z, acc[j][2]);
                    acc[j][3] = fmaf(xs, w4.w, acc[j][3]);
                }
            }
        }
    }
#pragma unroll
    for (int j = 0; j < RPT; ++j) {
        long r = rbase + j;
        if (r < nrows) {
            float4 o{acc[j][0], acc[j][1], acc[j][2], acc[j][3]};
            *(float4*)(H + (size_t)r * KOUT + 4 * g) = o;
        }
    }
}

// ---------------------------------------------------------------- propagation (CSR gather)
template <int K>
__global__ __launch_bounds__(256) void k_prop(const int* __restrict__ offs,
                                              const int2* __restrict__ csrp,
                                              const float* __restrict__ h,
                                              const float* __restrict__ dinv,
                                              const float* __restrict__ bias,
                                              float* __restrict__ out, int n) {
    constexpr int NPB = 256 / K;
    const int t  = threadIdx.x;
    const int ch = t & (K - 1);
    const int ln = t / K;
    const long nd = (long)blockIdx.x * NPB + ln;
    if (nd >= n) return;

    const int j0 = offs[nd], j1 = offs[nd + 1];
    float acc = 0.f;
    int j = j0;
    for (; j + 1 < j1; j += 2) {
        int2 p0 = csrp[j];
        int2 p1 = csrp[j + 1];
        float h0 = h[(size_t)p0.x * K + ch];
        float h1 = h[(size_t)p1.x * K + ch];
        acc = fmaf(__int_as_float(p0.y), h0, acc);
        acc = fmaf(__int_as_float(p1.y), h1, acc);
    }
    if (j < j1) {
        int2 p0 = csrp[j];
        acc = fmaf(__int_as_float(p0.y), h[(size_t)p0.x * K + ch], acc);
    }
    const float di = dinv[nd];
    const float hv = h[(size_t)nd * K + ch];
    out[(size_t)nd * K + ch] = fmaf(di, acc, fmaf(di * di, hv, bias[ch]));
}

// ---------------------------------------------------------------- layer 3 linear (32 -> 1)
__global__ void k_lin3(const float* __restrict__ X, const float* __restrict__ W3,
                       float* __restrict__ h3, int n) {
    long i = (long)blockIdx.x * BLK + threadIdx.x;
    if (i >= n) return;
    const float4* xr = (const float4*)(X + (size_t)i * 32);
    float acc = 0.f;
#pragma unroll
    for (int c = 0; c < 8; ++c) {
        float4 xv = xr[c];
        float4 wv = ((const float4*)W3)[c];
        acc = fmaf(fmaxf(xv.x, 0.f), wv.x, acc);
        acc = fmaf(fmaxf(xv.y, 0.f), wv.y, acc);
        acc = fmaf(fmaxf(xv.z, 0.f), wv.z, acc);
        acc = fmaf(fmaxf(xv.w, 0.f), wv.w, acc);
    }
    h3[i] = acc;
}

// ---------------------------------------------------------------- launch
extern "C" void kernel_launch(void* const* d_in, const int* in_sizes, int n_in,
                              void* d_out, int out_size, void* d_ws, size_t ws_size,
                              hipStream_t stream) {
    const float* x  = (const float*)d_in[0];
    const void*  ei = d_in[1];
    const float* ew = (const float*)d_in[2];
    const float* W1 = (const float*)d_in[3];
    const float* b1 = (const float*)d_in[4];
    const float* W2 = (const float*)d_in[5];
    const float* b2 = (const float*)d_in[6];
    const float* W3 = (const float*)d_in[7];
    const float* b3 = (const float*)d_in[8];
    float* out = (float*)d_out;

    const int n = in_sizes[0] / 512;
    const int e = in_sizes[2];

    char* ws = (char*)d_ws;
    size_t off = 0;
    auto alloc = [&](size_t bytes) {
        void* p = ws + off;
        off = (off + bytes + 255) & ~(size_t)255;
        return p;
    };
    int*    flag    = (int*)   alloc(4);
    int*    rows    = (int*)   alloc((size_t)e * 4);   // } aliased as bufA after scatter
    int*    cols    = (int*)   alloc((size_t)e * 4);   // }
    float*  bufA    = (float*)rows;                    // n*64 floats = 25.6MB <= 2*e*4
    int*    counts  = (int*)   alloc((size_t)n * 4);
    int*    offs    = (int*)   alloc((size_t)(n + 1) * 4);
    int*    cursor  = (int*)   alloc((size_t)n * 4);
    int*    bsum    = (int*)   alloc(512);
    int2*   csrp    = (int2*)  alloc((size_t)e * 8);
    float*  dinv    = (float*) alloc((size_t)n * 4);
    float*  bufB    = (float*) alloc((size_t)n * 64 * 4);
    __bf16* Wt      = (__bf16*)alloc((size_t)512 * 64 * 2);
    (void)ws_size; (void)n_in; (void)out_size;

    const int gb_e = (e + BLK - 1) / BLK;
    const int gb_n = (n + BLK - 1) / BLK;
    const int nb_scan = (n + 1023) / 1024;

    k_detect<<<1, 64, 0, stream>>>((const int*)ei, e, flag);
    k_cvt_idx<<<gb_e, BLK, 0, stream>>>(ei, e, flag, rows, cols);

    // CSR build (sorted by destination)
    k_zero_i<<<gb_n, BLK, 0, stream>>>(counts, n);
    k_hist<<<gb_e, BLK, 0, stream>>>(cols, counts, e);
    k_scan1<<<nb_scan, 256, 0, stream>>>(counts, counts, bsum, n);
    k_scan2<<<1, 128, 0, stream>>>(bsum, nb_scan);
    k_scan3<<<gb_n, BLK, 0, stream>>>(offs, cursor, counts, bsum, n, e);
    k_scatter<<<gb_e, BLK, 0, stream>>>(rows, cols, ew, cursor, csrp, e);
    k_deg<<<gb_n, BLK, 0, stream>>>(offs, csrp, dinv, n);
    k_csrnorm<<<gb_e, BLK, 0, stream>>>(csrp, dinv, e);

    // W1 -> bf16 transposed (64 KB, L2-resident)
    k_wcvt<<<(512 * 64 + BLK - 1) / BLK, BLK, 0, stream>>>(W1, Wt, 512, 64);

    // ---- layer 1: 512 -> 64 (bf16 MFMA; bufA aliases rows/cols, scatter done)
    {
        k_gemm1_mfma<<<(n + 63) / 64, 256, 0, stream>>>(x, Wt, bufA, n);
        k_prop<64><<<(n + 3) / 4, 256, 0, stream>>>(offs, csrp, bufA, dinv, b1, bufB, n);
    }
    // ---- layer 2: 64 -> 32 (f32, ReLU on GEMM input)
    {
        constexpr int ROWS = (256 / (32 / 4)) * 8;  // 256
        k_gemm<64, 32, 64, 8, true><<<(n + ROWS - 1) / ROWS, BLK, 0, stream>>>(bufB, W2, bufA, n);
        k_prop<32><<<(n + 7) / 8, 256, 0, stream>>>(offs, csrp, bufA, dinv, b2, bufB, n);
    }
    // ---- layer 3: 32 -> 1 (ReLU inside lin3)
    {
        k_lin3<<<gb_n, BLK, 0, stream>>>(bufB, W3, bufA, n);
        k_prop<1><<<(n + 255) / 256, 256, 0, stream>>>(offs, csrp, bufA, dinv, b3, out, n);
    }
}

// Round 4
// 615.729 us; speedup vs baseline: 8.1832x; 1.4082x over previous
//
#include <hip/hip_runtime.h>

constexpr int BLK = 256;
constexpr int NBLKBIN = 512;      // blocks for binning passes
constexpr int MAXNB   = 1024;     // max buckets (supports n <= 131072)

typedef __bf16 bf16x8 __attribute__((ext_vector_type(8)));
typedef float  f32x4  __attribute__((ext_vector_type(4)));

// ---------------------------------------------------------------- index width detect
__global__ void k_detect(const int* __restrict__ ei, int e, int* __restrict__ flag) {
    if (blockIdx.x == 0 && threadIdx.x == 0) {
        int is64 = 1;
        for (int i = 0; i < 16; ++i)
            if (ei[2 * i + 1] != 0) { is64 = 0; break; }
        *flag = is64;
    }
}

__device__ __forceinline__ int load_idx(const void* ei, size_t pos, int is64) {
    if (is64) return (int)((const long long*)ei)[pos];
    return ((const int*)ei)[pos];
}

__global__ void k_zero_i(int* __restrict__ p, int n) {
    long i = (long)blockIdx.x * BLK + threadIdx.x;
    if (i < n) p[i] = 0;
}

// ---------------------------------------------------------------- B1: coarse bucket histogram
__global__ __launch_bounds__(256) void k_binhist(const void* __restrict__ ei, int e,
                                                 const int* __restrict__ flag,
                                                 int* __restrict__ bucket_cnt, int nb) {
    __shared__ int hist[MAXNB];
    const int t = threadIdx.x;
    for (int b = t; b < nb; b += 256) hist[b] = 0;
    __syncthreads();
    const int is64 = *flag;
    const int chunk = (e + NBLKBIN - 1) / NBLKBIN;
    const int i0 = blockIdx.x * chunk;
    const int i1 = min(e, i0 + chunk);
    for (int i = i0 + t; i < i1; i += 256) {
        int dst = load_idx(ei, (size_t)e + i, is64);
        atomicAdd(&hist[dst >> 7], 1);
    }
    __syncthreads();
    for (int b = t; b < nb; b += 256) {
        int c = hist[b];
        if (c) atomicAdd(&bucket_cnt[b], c);
    }
}

// ---------------------------------------------------------------- B2: scan buckets
__global__ void k_scanbkt(const int* __restrict__ cnt, int* __restrict__ offs,
                          int* __restrict__ cursor, int nb, int e) {
    __shared__ int sh[256];
    const int t = threadIdx.x;
    const int base = t * 4;
    int v[4]; int s = 0;
#pragma unroll
    for (int k = 0; k < 4; ++k) {
        int i = base + k;
        v[k] = (i < nb) ? cnt[i] : 0;
        s += v[k];
    }
    sh[t] = s;
    __syncthreads();
    for (int d = 1; d < 256; d <<= 1) {
        int x = (t >= d) ? sh[t - d] : 0;
        __syncthreads();
        sh[t] += x;
        __syncthreads();
    }
    int excl = (t == 0) ? 0 : sh[t - 1];
#pragma unroll
    for (int k = 0; k < 4; ++k) {
        int i = base + k;
        if (i < nb) { offs[i] = excl; cursor[i] = excl; excl += v[k]; }
    }
    if (t == 255) offs[nb] = e;
}

// ---------------------------------------------------------------- B3: scatter into buckets
// payload: x = src | (dst&127)<<20 ; y = bits(weight)
__global__ __launch_bounds__(256) void k_binscatter(const void* __restrict__ ei,
                                                    const float* __restrict__ ew, int e,
                                                    const int* __restrict__ flag,
                                                    int* __restrict__ bucket_cursor,
                                                    int2* __restrict__ binned, int nb) {
    __shared__ int hist[MAXNB];
    const int t = threadIdx.x;
    for (int b = t; b < nb; b += 256) hist[b] = 0;
    __syncthreads();
    const int is64 = *flag;
    const int chunk = (e + NBLKBIN - 1) / NBLKBIN;
    const int i0 = blockIdx.x * chunk;
    const int i1 = min(e, i0 + chunk);
    // pass 1: local hist
    for (int i = i0 + t; i < i1; i += 256) {
        int dst = load_idx(ei, (size_t)e + i, is64);
        atomicAdd(&hist[dst >> 7], 1);
    }
    __syncthreads();
    // reserve: hist[b] becomes this block's absolute base in bucket b
    for (int b = t; b < nb; b += 256) {
        int c = hist[b];
        int base = 0;
        if (c) base = atomicAdd(&bucket_cursor[b], c);
        hist[b] = base;
    }
    __syncthreads();
    // pass 2: scatter
    for (int i = i0 + t; i < i1; i += 256) {
        int dst = load_idx(ei, (size_t)e + i, is64);
        int src = load_idx(ei, (size_t)i, is64);
        float w = ew[i];
        int bin = dst >> 7;
        int pos = atomicAdd(&hist[bin], 1);
        binned[pos] = make_int2(src | ((dst & 127) << 20), __float_as_int(w));
    }
}

// ---------------------------------------------------------------- B4: per-dst counts + degree/dinv
__global__ __launch_bounds__(256) void k_bucketcnt(const int* __restrict__ bucket_offs,
                                                   const int2* __restrict__ binned,
                                                   int* __restrict__ counts,
                                                   float* __restrict__ dinv, int n) {
    __shared__ int   icnt[128];
    __shared__ float facc[128];
    const int t = threadIdx.x;
    const int k = blockIdx.x;
    if (t < 128) { icnt[t] = 0; facc[t] = 0.f; }
    __syncthreads();
    const int j0 = bucket_offs[k], j1 = bucket_offs[k + 1];
    for (int j = j0 + t; j < j1; j += 256) {
        int2 p = binned[j];
        int dl = ((unsigned)p.x) >> 20;
        atomicAdd(&icnt[dl], 1);
        atomicAdd(&facc[dl], __int_as_float(p.y));
    }
    __syncthreads();
    if (t < 128) {
        int nd = k * 128 + t;
        if (nd < n) {
            counts[nd] = icnt[t];
            dinv[nd] = rsqrtf(1.0f + facc[t]);
        }
    }
}

// ---------------------------------------------------------------- scan over nodes (counts -> offs)
__global__ void k_scan1(const int* __restrict__ in, int* __restrict__ out,
                        int* __restrict__ bsum, int n) {
    __shared__ int sh[256];
    const int t = threadIdx.x;
    const int base = blockIdx.x * 1024 + t * 4;
    int v[4];
    int s = 0;
#pragma unroll
    for (int k = 0; k < 4; ++k) {
        int i = base + k;
        v[k] = (i < n) ? in[i] : 0;
        s += v[k];
    }
    sh[t] = s;
    __syncthreads();
    for (int d = 1; d < 256; d <<= 1) {
        int x = (t >= d) ? sh[t - d] : 0;
        __syncthreads();
        sh[t] += x;
        __syncthreads();
    }
    int excl = (t == 0) ? 0 : sh[t - 1];
    if (t == 255) bsum[blockIdx.x] = sh[255];
#pragma unroll
    for (int k = 0; k < 4; ++k) {
        int i = base + k;
        if (i < n) { out[i] = excl; excl += v[k]; }
    }
}

__global__ void k_scan2(int* __restrict__ bsum, int nb) {
    __shared__ int sh[128];
    const int t = threadIdx.x;
    sh[t] = (t < nb) ? bsum[t] : 0;
    __syncthreads();
    for (int d = 1; d < 128; d <<= 1) {
        int x = (t >= d) ? sh[t - d] : 0;
        __syncthreads();
        sh[t] += x;
        __syncthreads();
    }
    if (t < nb) bsum[t] = (t == 0) ? 0 : sh[t - 1];
}

__global__ void k_scan3(int* __restrict__ offs, const int* __restrict__ scanned,
                        const int* __restrict__ bsum, int n, int e) {
    long i = (long)blockIdx.x * BLK + threadIdx.x;
    if (i < n) offs[i] = scanned[i] + bsum[i >> 10];
    if (i == 0) offs[n] = e;
}

// ---------------------------------------------------------------- B5: exact CSR placement (+ fold dinv[src])
__global__ __launch_bounds__(256) void k_place(const int* __restrict__ bucket_offs,
                                               const int2* __restrict__ binned,
                                               const int* __restrict__ offs,
                                               const float* __restrict__ dinv,
                                               int2* __restrict__ csrp, int n) {
    __shared__ int cur[128];
    const int t = threadIdx.x;
    const int k = blockIdx.x;
    if (t < 128) {
        int nd = k * 128 + t;
        cur[t] = (nd < n) ? offs[nd] : 0;
    }
    __syncthreads();
    const int j0 = bucket_offs[k], j1 = bucket_offs[k + 1];
    for (int j = j0 + t; j < j1; j += 256) {
        int2 p = binned[j];
        int dl  = ((unsigned)p.x) >> 20;
        int src = p.x & 0xFFFFF;
        int pos = atomicAdd(&cur[dl], 1);
        float w2 = __int_as_float(p.y) * dinv[src];
        csrp[pos] = make_int2(src, __float_as_int(w2));
    }
}

// ---------------------------------------------------------------- W1 -> bf16 transposed [KOUT][KIN]
__global__ void k_wcvt(const float* __restrict__ W, __bf16* __restrict__ Wt,
                       int kin, int kout) {
    int i = blockIdx.x * BLK + threadIdx.x;
    if (i >= kin * kout) return;
    int k = i / kout, nn = i % kout;
    Wt[(size_t)nn * kin + k] = (__bf16)W[i];
}

// ---------------------------------------------------------------- GEMM1: bf16 MFMA
__global__ __launch_bounds__(256) void k_gemm1_mfma(const float* __restrict__ X,
                                                    const __bf16* __restrict__ Wt,
                                                    float* __restrict__ H, int nrows) {
    const int wave = threadIdx.x >> 6;
    const int lane = threadIdx.x & 63;
    const int l15  = lane & 15;
    const int lq   = lane >> 4;
    const long rbase = (long)blockIdx.x * 64 + wave * 16;

    long arow = rbase + l15;
    if (arow >= nrows) arow = nrows - 1;
    const float* xr = X + (size_t)arow * 512 + lq * 8;

    f32x4 acc[4] = {{0.f,0.f,0.f,0.f},{0.f,0.f,0.f,0.f},{0.f,0.f,0.f,0.f},{0.f,0.f,0.f,0.f}};

    for (int k0 = 0; k0 < 512; k0 += 32) {
        float4 a0 = *(const float4*)(xr + k0);
        float4 a1 = *(const float4*)(xr + k0 + 4);
        bf16x8 af;
        af[0] = (__bf16)a0.x; af[1] = (__bf16)a0.y; af[2] = (__bf16)a0.z; af[3] = (__bf16)a0.w;
        af[4] = (__bf16)a1.x; af[5] = (__bf16)a1.y; af[6] = (__bf16)a1.z; af[7] = (__bf16)a1.w;
#pragma unroll
        for (int t = 0; t < 4; ++t) {
            bf16x8 bf_ = *(const bf16x8*)(Wt + (size_t)(t * 16 + l15) * 512 + k0 + lq * 8);
            acc[t] = __builtin_amdgcn_mfma_f32_16x16x32_bf16(af, bf_, acc[t], 0, 0, 0);
        }
    }
#pragma unroll
    for (int t = 0; t < 4; ++t) {
#pragma unroll
        for (int r = 0; r < 4; ++r) {
            long row = rbase + lq * 4 + r;
            if (row < nrows) H[(size_t)row * 64 + t * 16 + l15] = acc[t][r];
        }
    }
}

// ---------------------------------------------------------------- dense GEMM (f32 VALU) for layer 2
template <int KIN, int KOUT, int CTILE, int RPT, bool RELU_IN>
__global__ __launch_bounds__(256) void k_gemm(const float* __restrict__ X,
                                              const float* __restrict__ W,
                                              float* __restrict__ H, int nrows) {
    constexpr int TPR  = KOUT / 4;
    constexpr int QG   = 256 / TPR;
    constexpr int ROWS = QG * RPT;
    __shared__ float Ws[CTILE * KOUT];

    const int g = threadIdx.x & (TPR - 1);
    const int q = threadIdx.x / TPR;
    const long rbase = (long)blockIdx.x * ROWS + (long)q * RPT;

    float acc[RPT][4];
#pragma unroll
    for (int j = 0; j < RPT; ++j) { acc[j][0] = acc[j][1] = acc[j][2] = acc[j][3] = 0.f; }

    for (int c0 = 0; c0 < KIN; c0 += CTILE) {
        __syncthreads();
#pragma unroll
        for (int i = threadIdx.x; i < CTILE * KOUT / 4; i += 256)
            ((float4*)Ws)[i] = ((const float4*)(W + (size_t)c0 * KOUT))[i];
        __syncthreads();

#pragma unroll 4
        for (int c = 0; c < CTILE; c += 4) {
            float4 xv[RPT];
#pragma unroll
            for (int j = 0; j < RPT; ++j) {
                long r = rbase + j;
                if (r < nrows) {
                    xv[j] = *(const float4*)(X + (size_t)r * KIN + c0 + c);
                    if (RELU_IN) {
                        xv[j].x = fmaxf(xv[j].x, 0.f);
                        xv[j].y = fmaxf(xv[j].y, 0.f);
                        xv[j].z = fmaxf(xv[j].z, 0.f);
                        xv[j].w = fmaxf(xv[j].w, 0.f);
                    }
                } else {
                    xv[j] = float4{0.f, 0.f, 0.f, 0.f};
                }
            }
#pragma unroll
            for (int cc = 0; cc < 4; ++cc) {
                const float4 w4 = *(const float4*)(&Ws[(c + cc) * KOUT + 4 * g]);
#pragma unroll
                for (int j = 0; j < RPT; ++j) {
                    const float xs = (&xv[j].x)[cc];
                    acc[j][0] = fmaf(xs, w4.x, acc[j][0]);
                    acc[j][1] = fmaf(xs, w4.y, acc[j][1]);
                    acc[j][2] = fmaf(xs, w4.z, acc[j][2]);
                    acc[j][3] = fmaf(xs, w4.w, acc[j][3]);
                }
            }
        }
    }
#pragma unroll
    for (int j = 0; j < RPT; ++j) {
        long r = rbase + j;
        if (r < nrows) {
            float4 o{acc[j][0], acc[j][1], acc[j][2], acc[j][3]};
            *(float4*)(H + (size_t)r * KOUT + 4 * g) = o;
        }
    }
}

// ---------------------------------------------------------------- propagation (CSR gather)
template <int K>
__global__ __launch_bounds__(256) void k_prop(const int* __restrict__ offs,
                                              const int2* __restrict__ csrp,
                                              const float* __restrict__ h,
                                              const float* __restrict__ dinv,
                                              const float* __restrict__ bias,
                                              float* __restrict__ out, int n) {
    constexpr int NPB = 256 / K;
    const int t  = threadIdx.x;
    const int ch = t & (K - 1);
    const int ln = t / K;
    const long nd = (long)blockIdx.x * NPB + ln;
    if (nd >= n) return;

    const int j0 = offs[nd], j1 = offs[nd + 1];
    float acc = 0.f;
    int j = j0;
    for (; j + 1 < j1; j += 2) {
        int2 p0 = csrp[j];
        int2 p1 = csrp[j + 1];
        float h0 = h[(size_t)p0.x * K + ch];
        float h1 = h[(size_t)p1.x * K + ch];
        acc = fmaf(__int_as_float(p0.y), h0, acc);
        acc = fmaf(__int_as_float(p1.y), h1, acc);
    }
    if (j < j1) {
        int2 p0 = csrp[j];
        acc = fmaf(__int_as_float(p0.y), h[(size_t)p0.x * K + ch], acc);
    }
    const float di = dinv[nd];
    const float hv = h[(size_t)nd * K + ch];
    out[(size_t)nd * K + ch] = fmaf(di, acc, fmaf(di * di, hv, bias[ch]));
}

// ---------------------------------------------------------------- layer 3 linear (32 -> 1)
__global__ void k_lin3(const float* __restrict__ X, const float* __restrict__ W3,
                       float* __restrict__ h3, int n) {
    long i = (long)blockIdx.x * BLK + threadIdx.x;
    if (i >= n) return;
    const float4* xr = (const float4*)(X + (size_t)i * 32);
    float acc = 0.f;
#pragma unroll
    for (int c = 0; c < 8; ++c) {
        float4 xv = xr[c];
        float4 wv = ((const float4*)W3)[c];
        acc = fmaf(fmaxf(xv.x, 0.f), wv.x, acc);
        acc = fmaf(fmaxf(xv.y, 0.f), wv.y, acc);
        acc = fmaf(fmaxf(xv.z, 0.f), wv.z, acc);
        acc = fmaf(fmaxf(xv.w, 0.f), wv.w, acc);
    }
    h3[i] = acc;
}

// ---------------------------------------------------------------- launch
extern "C" void kernel_launch(void* const* d_in, const int* in_sizes, int n_in,
                              void* d_out, int out_size, void* d_ws, size_t ws_size,
                              hipStream_t stream) {
    const float* x  = (const float*)d_in[0];
    const void*  ei = d_in[1];
    const float* ew = (const float*)d_in[2];
    const float* W1 = (const float*)d_in[3];
    const float* b1 = (const float*)d_in[4];
    const float* W2 = (const float*)d_in[5];
    const float* b2 = (const float*)d_in[6];
    const float* W3 = (const float*)d_in[7];
    const float* b3 = (const float*)d_in[8];
    float* out = (float*)d_out;

    const int n = in_sizes[0] / 512;
    const int e = in_sizes[2];
    const int nb = (n + 127) >> 7;   // buckets of 128 dst nodes (<= MAXNB for n<=131072)

    char* ws = (char*)d_ws;
    size_t off = 0;
    auto alloc = [&](size_t bytes) {
        void* p = ws + off;
        off = (off + bytes + 255) & ~(size_t)255;
        return p;
    };
    int*    flag     = (int*)   alloc(4);
    int2*   binned   = (int2*)  alloc((size_t)e * 8);   // aliased as bufA after k_place
    float*  bufA     = (float*) binned;                 // n*64*4 = 25.6MB <= e*8
    int*    bkt_cnt  = (int*)   alloc((size_t)(MAXNB + 1) * 4);
    int*    bkt_offs = (int*)   alloc((size_t)(MAXNB + 1) * 4);
    int*    bkt_cur  = (int*)   alloc((size_t)(MAXNB + 1) * 4);
    int*    counts   = (int*)   alloc((size_t)n * 4);
    int*    offs     = (int*)   alloc((size_t)(n + 1) * 4);
    int*    bsum     = (int*)   alloc(512);
    int2*   csrp     = (int2*)  alloc((size_t)e * 8);
    float*  dinv     = (float*) alloc((size_t)n * 4);
    float*  bufB     = (float*) alloc((size_t)n * 64 * 4);
    __bf16* Wt       = (__bf16*)alloc((size_t)512 * 64 * 2);
    (void)ws_size; (void)n_in; (void)out_size;

    const int gb_n = (n + BLK - 1) / BLK;
    const int nb_scan = (n + 1023) / 1024;

    k_detect<<<1, 64, 0, stream>>>((const int*)ei, e, flag);

    // ---- CSR build via 2-level binning
    k_zero_i<<<(nb + BLK - 1) / BLK, BLK, 0, stream>>>(bkt_cnt, nb);
    k_binhist<<<NBLKBIN, 256, 0, stream>>>(ei, e, flag, bkt_cnt, nb);
    k_scanbkt<<<1, 256, 0, stream>>>(bkt_cnt, bkt_offs, bkt_cur, nb, e);
    k_binscatter<<<NBLKBIN, 256, 0, stream>>>(ei, ew, e, flag, bkt_cur, binned, nb);
    k_bucketcnt<<<nb, 256, 0, stream>>>(bkt_offs, binned, counts, dinv, n);
    k_scan1<<<nb_scan, 256, 0, stream>>>(counts, counts, bsum, n);
    k_scan2<<<1, 128, 0, stream>>>(bsum, nb_scan);
    k_scan3<<<gb_n, BLK, 0, stream>>>(offs, counts, bsum, n, e);
    k_place<<<nb, 256, 0, stream>>>(bkt_offs, binned, offs, dinv, csrp, n);

    // W1 -> bf16 transposed (64 KB, L2-resident)
    k_wcvt<<<(512 * 64 + BLK - 1) / BLK, BLK, 0, stream>>>(W1, Wt, 512, 64);

    // ---- layer 1: 512 -> 64 (bf16 MFMA; bufA aliases binned, which is dead now)
    {
        k_gemm1_mfma<<<(n + 63) / 64, 256, 0, stream>>>(x, Wt, bufA, n);
        k_prop<64><<<(n + 3) / 4, 256, 0, stream>>>(offs, csrp, bufA, dinv, b1, bufB, n);
    }
    // ---- layer 2: 64 -> 32 (f32, ReLU on GEMM input)
    {
        constexpr int ROWS = (256 / (32 / 4)) * 8;  // 256
        k_gemm<64, 32, 64, 8, true><<<(n + ROWS - 1) / ROWS, BLK, 0, stream>>>(bufB, W2, bufA, n);
        k_prop<32><<<(n + 7) / 8, 256, 0, stream>>>(offs, csrp, bufA, dinv, b2, bufB, n);
    }
    // ---- layer 3: 32 -> 1 (ReLU inside lin3)
    {
        k_lin3<<<gb_n, BLK, 0, stream>>>(bufB, W3, bufA, n);
        k_prop<1><<<(n + 255) / 256, 256, 0, stream>>>(offs, csrp, bufA, dinv, b3, out, n);
    }
}

// Round 5
// 476.577 us; speedup vs baseline: 10.5726x; 1.2920x over previous
//
#include <hip/hip_runtime.h>

constexpr int BLK = 256;
constexpr int NBLKBIN = 512;      // blocks for binning passes
constexpr int MAXNB   = 1024;     // max buckets (supports n <= 131072)

typedef __bf16 bf16x8 __attribute__((ext_vector_type(8)));
typedef float  f32x4  __attribute__((ext_vector_type(4)));

__device__ __forceinline__ float blo(unsigned u) { return __uint_as_float(u << 16); }
__device__ __forceinline__ float bhi(unsigned u) { return __uint_as_float(u & 0xffff0000u); }

// ---------------------------------------------------------------- index width detect
__global__ void k_detect(const int* __restrict__ ei, int e, int* __restrict__ flag) {
    if (blockIdx.x == 0 && threadIdx.x == 0) {
        int is64 = 1;
        for (int i = 0; i < 16; ++i)
            if (ei[2 * i + 1] != 0) { is64 = 0; break; }
        *flag = is64;
    }
}

__device__ __forceinline__ int load_idx(const void* ei, size_t pos, int is64) {
    if (is64) return (int)((const long long*)ei)[pos];
    return ((const int*)ei)[pos];
}

__global__ void k_zero_i(int* __restrict__ p, int n) {
    long i = (long)blockIdx.x * BLK + threadIdx.x;
    if (i < n) p[i] = 0;
}

// ---------------------------------------------------------------- B1: coarse bucket histogram
__global__ __launch_bounds__(256) void k_binhist(const void* __restrict__ ei, int e,
                                                 const int* __restrict__ flag,
                                                 int* __restrict__ bucket_cnt, int nb) {
    __shared__ int hist[MAXNB];
    const int t = threadIdx.x;
    for (int b = t; b < nb; b += 256) hist[b] = 0;
    __syncthreads();
    const int is64 = *flag;
    const int chunk = (e + NBLKBIN - 1) / NBLKBIN;
    const int i0 = blockIdx.x * chunk;
    const int i1 = min(e, i0 + chunk);
    for (int i = i0 + t; i < i1; i += 256) {
        int dst = load_idx(ei, (size_t)e + i, is64);
        atomicAdd(&hist[dst >> 7], 1);
    }
    __syncthreads();
    for (int b = t; b < nb; b += 256) {
        int c = hist[b];
        if (c) atomicAdd(&bucket_cnt[b], c);
    }
}

// ---------------------------------------------------------------- B2: scan buckets
__global__ void k_scanbkt(const int* __restrict__ cnt, int* __restrict__ offs,
                          int* __restrict__ cursor, int nb, int e) {
    __shared__ int sh[256];
    const int t = threadIdx.x;
    const int base = t * 4;
    int v[4]; int s = 0;
#pragma unroll
    for (int k = 0; k < 4; ++k) {
        int i = base + k;
        v[k] = (i < nb) ? cnt[i] : 0;
        s += v[k];
    }
    sh[t] = s;
    __syncthreads();
    for (int d = 1; d < 256; d <<= 1) {
        int x = (t >= d) ? sh[t - d] : 0;
        __syncthreads();
        sh[t] += x;
        __syncthreads();
    }
    int excl = (t == 0) ? 0 : sh[t - 1];
#pragma unroll
    for (int k = 0; k < 4; ++k) {
        int i = base + k;
        if (i < nb) { offs[i] = excl; cursor[i] = excl; excl += v[k]; }
    }
    if (t == 255) offs[nb] = e;
}

// ---------------------------------------------------------------- B3: scatter into buckets
// payload: x = src | (dst&127)<<20 ; y = bits(weight)
__global__ __launch_bounds__(256) void k_binscatter(const void* __restrict__ ei,
                                                    const float* __restrict__ ew, int e,
                                                    const int* __restrict__ flag,
                                                    int* __restrict__ bucket_cursor,
                                                    int2* __restrict__ binned, int nb) {
    __shared__ int hist[MAXNB];
    const int t = threadIdx.x;
    for (int b = t; b < nb; b += 256) hist[b] = 0;
    __syncthreads();
    const int is64 = *flag;
    const int chunk = (e + NBLKBIN - 1) / NBLKBIN;
    const int i0 = blockIdx.x * chunk;
    const int i1 = min(e, i0 + chunk);
    for (int i = i0 + t; i < i1; i += 256) {
        int dst = load_idx(ei, (size_t)e + i, is64);
        atomicAdd(&hist[dst >> 7], 1);
    }
    __syncthreads();
    for (int b = t; b < nb; b += 256) {
        int c = hist[b];
        int base = 0;
        if (c) base = atomicAdd(&bucket_cursor[b], c);
        hist[b] = base;
    }
    __syncthreads();
    for (int i = i0 + t; i < i1; i += 256) {
        int dst = load_idx(ei, (size_t)e + i, is64);
        int src = load_idx(ei, (size_t)i, is64);
        float w = ew[i];
        int bin = dst >> 7;
        int pos = atomicAdd(&hist[bin], 1);
        binned[pos] = make_int2(src | ((dst & 127) << 20), __float_as_int(w));
    }
}

// ---------------------------------------------------------------- B4: per-dst counts + degree/dinv
__global__ __launch_bounds__(256) void k_bucketcnt(const int* __restrict__ bucket_offs,
                                                   const int2* __restrict__ binned,
                                                   int* __restrict__ counts,
                                                   float* __restrict__ dinv, int n) {
    __shared__ int   icnt[128];
    __shared__ float facc[128];
    const int t = threadIdx.x;
    const int k = blockIdx.x;
    if (t < 128) { icnt[t] = 0; facc[t] = 0.f; }
    __syncthreads();
    const int j0 = bucket_offs[k], j1 = bucket_offs[k + 1];
    for (int j = j0 + t; j < j1; j += 256) {
        int2 p = binned[j];
        int dl = ((unsigned)p.x) >> 20;
        atomicAdd(&icnt[dl], 1);
        atomicAdd(&facc[dl], __int_as_float(p.y));
    }
    __syncthreads();
    if (t < 128) {
        int nd = k * 128 + t;
        if (nd < n) {
            counts[nd] = icnt[t];
            dinv[nd] = rsqrtf(1.0f + facc[t]);
        }
    }
}

// ---------------------------------------------------------------- scan over nodes (counts -> offs)
__global__ void k_scan1(const int* __restrict__ in, int* __restrict__ out,
                        int* __restrict__ bsum, int n) {
    __shared__ int sh[256];
    const int t = threadIdx.x;
    const int base = blockIdx.x * 1024 + t * 4;
    int v[4];
    int s = 0;
#pragma unroll
    for (int k = 0; k < 4; ++k) {
        int i = base + k;
        v[k] = (i < n) ? in[i] : 0;
        s += v[k];
    }
    sh[t] = s;
    __syncthreads();
    for (int d = 1; d < 256; d <<= 1) {
        int x = (t >= d) ? sh[t - d] : 0;
        __syncthreads();
        sh[t] += x;
        __syncthreads();
    }
    int excl = (t == 0) ? 0 : sh[t - 1];
    if (t == 255) bsum[blockIdx.x] = sh[255];
#pragma unroll
    for (int k = 0; k < 4; ++k) {
        int i = base + k;
        if (i < n) { out[i] = excl; excl += v[k]; }
    }
}

__global__ void k_scan2(int* __restrict__ bsum, int nb) {
    __shared__ int sh[128];
    const int t = threadIdx.x;
    sh[t] = (t < nb) ? bsum[t] : 0;
    __syncthreads();
    for (int d = 1; d < 128; d <<= 1) {
        int x = (t >= d) ? sh[t - d] : 0;
        __syncthreads();
        sh[t] += x;
        __syncthreads();
    }
    if (t < nb) bsum[t] = (t == 0) ? 0 : sh[t - 1];
}

__global__ void k_scan3(int* __restrict__ offs, const int* __restrict__ scanned,
                        const int* __restrict__ bsum, int n, int e) {
    long i = (long)blockIdx.x * BLK + threadIdx.x;
    if (i < n) offs[i] = scanned[i] + bsum[i >> 10];
    if (i == 0) offs[n] = e;
}

// ---------------------------------------------------------------- B5: exact CSR placement (+ fold dinv[src])
__global__ __launch_bounds__(256) void k_place(const int* __restrict__ bucket_offs,
                                               const int2* __restrict__ binned,
                                               const int* __restrict__ offs,
                                               const float* __restrict__ dinv,
                                               int2* __restrict__ csrp, int n) {
    __shared__ int cur[128];
    const int t = threadIdx.x;
    const int k = blockIdx.x;
    if (t < 128) {
        int nd = k * 128 + t;
        cur[t] = (nd < n) ? offs[nd] : 0;
    }
    __syncthreads();
    const int j0 = bucket_offs[k], j1 = bucket_offs[k + 1];
    for (int j = j0 + t; j < j1; j += 256) {
        int2 p = binned[j];
        int dl  = ((unsigned)p.x) >> 20;
        int src = p.x & 0xFFFFF;
        int pos = atomicAdd(&cur[dl], 1);
        float w2 = __int_as_float(p.y) * dinv[src];
        csrp[pos] = make_int2(src, __float_as_int(w2));
    }
}

// ---------------------------------------------------------------- W1 -> bf16 fragment-major
// Wtf[k0c][t][lane][j] ; col = t*16 + (lane&15), k = k0c*32 + (lane>>4)*8 + j
__global__ void k_wcvt_frag(const float* __restrict__ W, __bf16* __restrict__ Wtf) {
    int i = blockIdx.x * BLK + threadIdx.x;       // over 16*4*64 = 4096
    if (i >= 4096) return;
    int lane = i & 63;
    int t    = (i >> 6) & 3;
    int k0c  = i >> 8;
    int col  = t * 16 + (lane & 15);
    int kbase = k0c * 32 + (lane >> 4) * 8;
    bf16x8 v;
#pragma unroll
    for (int j = 0; j < 8; ++j) v[j] = (__bf16)W[(size_t)(kbase + j) * 64 + col];
    *(bf16x8*)(Wtf + (size_t)i * 8) = v;
}

// ---------------------------------------------------------------- GEMM1: bf16 MFMA, bf16 output
__global__ __launch_bounds__(256) void k_gemm1_mfma(const float* __restrict__ X,
                                                    const __bf16* __restrict__ Wtf,
                                                    __bf16* __restrict__ H, int nrows) {
    const int wave = threadIdx.x >> 6;
    const int lane = threadIdx.x & 63;
    const int l15  = lane & 15;
    const int lq   = lane >> 4;
    const long rbase = (long)blockIdx.x * 64 + wave * 16;

    long arow = rbase + l15;
    if (arow >= nrows) arow = nrows - 1;
    const float* xr = X + (size_t)arow * 512 + lq * 8;

    f32x4 acc[4] = {{0.f,0.f,0.f,0.f},{0.f,0.f,0.f,0.f},{0.f,0.f,0.f,0.f},{0.f,0.f,0.f,0.f}};

#pragma unroll 2
    for (int k0c = 0; k0c < 16; ++k0c) {
        float4 a0 = *(const float4*)(xr + k0c * 32);
        float4 a1 = *(const float4*)(xr + k0c * 32 + 4);
        bf16x8 af;
        af[0] = (__bf16)a0.x; af[1] = (__bf16)a0.y; af[2] = (__bf16)a0.z; af[3] = (__bf16)a0.w;
        af[4] = (__bf16)a1.x; af[5] = (__bf16)a1.y; af[6] = (__bf16)a1.z; af[7] = (__bf16)a1.w;
#pragma unroll
        for (int t = 0; t < 4; ++t) {
            // fragment-major: wave-contiguous 1KB per (k0c, t)
            bf16x8 bf_ = *(const bf16x8*)(Wtf + ((size_t)(k0c * 4 + t) * 64 + lane) * 8);
            acc[t] = __builtin_amdgcn_mfma_f32_16x16x32_bf16(af, bf_, acc[t], 0, 0, 0);
        }
    }
    // C layout: col = l15, row = lq*4 + reg
#pragma unroll
    for (int t = 0; t < 4; ++t) {
#pragma unroll
        for (int r = 0; r < 4; ++r) {
            long row = rbase + lq * 4 + r;
            if (row < nrows) H[(size_t)row * 64 + t * 16 + l15] = (__bf16)acc[t][r];
        }
    }
}

// ---------------------------------------------------------------- dense GEMM (f32 VALU, bf16 out) layer 2
template <int KIN, int KOUT, int CTILE, int RPT, bool RELU_IN>
__global__ __launch_bounds__(256) void k_gemm(const float* __restrict__ X,
                                              const float* __restrict__ W,
                                              __bf16* __restrict__ H, int nrows) {
    constexpr int TPR  = KOUT / 4;
    constexpr int QG   = 256 / TPR;
    constexpr int ROWS = QG * RPT;
    __shared__ float Ws[CTILE * KOUT];

    const int g = threadIdx.x & (TPR - 1);
    const int q = threadIdx.x / TPR;
    const long rbase = (long)blockIdx.x * ROWS + (long)q * RPT;

    float acc[RPT][4];
#pragma unroll
    for (int j = 0; j < RPT; ++j) { acc[j][0] = acc[j][1] = acc[j][2] = acc[j][3] = 0.f; }

    for (int c0 = 0; c0 < KIN; c0 += CTILE) {
        __syncthreads();
#pragma unroll
        for (int i = threadIdx.x; i < CTILE * KOUT / 4; i += 256)
            ((float4*)Ws)[i] = ((const float4*)(W + (size_t)c0 * KOUT))[i];
        __syncthreads();

#pragma unroll 4
        for (int c = 0; c < CTILE; c += 4) {
            float4 xv[RPT];
#pragma unroll
            for (int j = 0; j < RPT; ++j) {
                long r = rbase + j;
                if (r < nrows) {
                    xv[j] = *(const float4*)(X + (size_t)r * KIN + c0 + c);
                    if (RELU_IN) {
                        xv[j].x = fmaxf(xv[j].x, 0.f);
                        xv[j].y = fmaxf(xv[j].y, 0.f);
                        xv[j].z = fmaxf(xv[j].z, 0.f);
                        xv[j].w = fmaxf(xv[j].w, 0.f);
                    }
                } else {
                    xv[j] = float4{0.f, 0.f, 0.f, 0.f};
                }
            }
#pragma unroll
            for (int cc = 0; cc < 4; ++cc) {
                const float4 w4 = *(const float4*)(&Ws[(c + cc) * KOUT + 4 * g]);
#pragma unroll
                for (int j = 0; j < RPT; ++j) {
                    const float xs = (&xv[j].x)[cc];
                    acc[j][0] = fmaf(xs, w4.x, acc[j][0]);
                    acc[j][1] = fmaf(xs, w4.y, acc[j][1]);
                    acc[j][2] = fmaf(xs, w4.z, acc[j][2]);
                    acc[j][3] = fmaf(xs, w4.w, acc[j][3]);
                }
            }
        }
    }
#pragma unroll
    for (int j = 0; j < RPT; ++j) {
        long r = rbase + j;
        if (r < nrows) {
            ushort4 o;
            o.x = __float_as_uint(acc[j][0] + 0.f) >> 16;  // placeholder; real cvt below
            // use proper RNE conversion via compiler cast:
            __bf16 b0 = (__bf16)acc[j][0], b1 = (__bf16)acc[j][1];
            __bf16 b2 = (__bf16)acc[j][2], b3 = (__bf16)acc[j][3];
            __bf16* dst = H + (size_t)r * KOUT + 4 * g;
            dst[0] = b0; dst[1] = b1; dst[2] = b2; dst[3] = b3;
        }
    }
}

// ---------------------------------------------------------------- propagation (CSR gather, bf16 h)
// lane owns 2 channels (one u32 load); K/2 lanes per node, 2*64/K nodes per wave
template <int K>
__global__ __launch_bounds__(256) void k_prop_bf(const int* __restrict__ offs,
                                                 const int2* __restrict__ csrp,
                                                 const __bf16* __restrict__ hb,
                                                 const float* __restrict__ dinv,
                                                 const float* __restrict__ bias,
                                                 float* __restrict__ out, int n) {
    constexpr int SUB = K / 2;           // lanes per node
    constexpr int NPW = 64 / SUB;        // nodes per wave
    constexpr int NPB = 4 * NPW;         // nodes per block
    const int t    = threadIdx.x;
    const int lane = t & 63;
    const int wave = t >> 6;
    const int chp  = lane & (SUB - 1);   // channel pair index
    const int sub  = lane / SUB;
    const long nd  = (long)blockIdx.x * NPB + wave * NPW + sub;
    if (nd >= n) return;

    const unsigned short* h = (const unsigned short*)hb;
    const int j0 = offs[nd], j1 = offs[nd + 1];
    float a0 = 0.f, a1 = 0.f;
    int j = j0;
    for (; j + 1 < j1; j += 2) {
        int2 p0 = csrp[j];
        int2 p1 = csrp[j + 1];
        unsigned u0 = *(const unsigned*)(h + (size_t)p0.x * K + 2 * chp);
        unsigned u1 = *(const unsigned*)(h + (size_t)p1.x * K + 2 * chp);
        float w0 = __int_as_float(p0.y), w1 = __int_as_float(p1.y);
        a0 = fmaf(w0, blo(u0), a0);
        a1 = fmaf(w0, bhi(u0), a1);
        a0 = fmaf(w1, blo(u1), a0);
        a1 = fmaf(w1, bhi(u1), a1);
    }
    if (j < j1) {
        int2 p0 = csrp[j];
        unsigned u0 = *(const unsigned*)(h + (size_t)p0.x * K + 2 * chp);
        float w0 = __int_as_float(p0.y);
        a0 = fmaf(w0, blo(u0), a0);
        a1 = fmaf(w0, bhi(u0), a1);
    }
    const float di = dinv[nd];
    const float s  = di * di;
    unsigned us = *(const unsigned*)(h + (size_t)nd * K + 2 * chp);
    float2 bv = *(const float2*)(bias + 2 * chp);
    float o0 = fmaf(di, a0, fmaf(s, blo(us), bv.x));
    float o1 = fmaf(di, a1, fmaf(s, bhi(us), bv.y));
    *(float2*)(out + (size_t)nd * K + 2 * chp) = make_float2(o0, o1);
}

// ---------------------------------------------------------------- layer 3 linear (32 -> 1, f32 in)
__global__ void k_lin3(const float* __restrict__ X, const float* __restrict__ W3,
                       float* __restrict__ h3, int n) {
    long i = (long)blockIdx.x * BLK + threadIdx.x;
    if (i >= n) return;
    const float4* xr = (const float4*)(X + (size_t)i * 32);
    float acc = 0.f;
#pragma unroll
    for (int c = 0; c < 8; ++c) {
        float4 xv = xr[c];
        float4 wv = ((const float4*)W3)[c];
        acc = fmaf(fmaxf(xv.x, 0.f), wv.x, acc);
        acc = fmaf(fmaxf(xv.y, 0.f), wv.y, acc);
        acc = fmaf(fmaxf(xv.z, 0.f), wv.z, acc);
        acc = fmaf(fmaxf(xv.w, 0.f), wv.w, acc);
    }
    h3[i] = acc;
}

// output prop: K=1, f32 h3 (one lane per node)
__global__ __launch_bounds__(256) void k_prop1(const int* __restrict__ offs,
                                               const int2* __restrict__ csrp,
                                               const float* __restrict__ h,
                                               const float* __restrict__ dinv,
                                               const float* __restrict__ bias,
                                               float* __restrict__ out, int n) {
    long nd = (long)blockIdx.x * BLK + threadIdx.x;
    if (nd >= n) return;
    const int j0 = offs[nd], j1 = offs[nd + 1];
    float acc = 0.f;
    int j = j0;
    for (; j + 1 < j1; j += 2) {
        int2 p0 = csrp[j];
        int2 p1 = csrp[j + 1];
        acc = fmaf(__int_as_float(p0.y), h[p0.x], acc);
        acc = fmaf(__int_as_float(p1.y), h[p1.x], acc);
    }
    if (j < j1) {
        int2 p0 = csrp[j];
        acc = fmaf(__int_as_float(p0.y), h[p0.x], acc);
    }
    const float di = dinv[nd];
    out[nd] = fmaf(di, acc, fmaf(di * di, h[nd], bias[0]));
}

// ---------------------------------------------------------------- launch
extern "C" void kernel_launch(void* const* d_in, const int* in_sizes, int n_in,
                              void* d_out, int out_size, void* d_ws, size_t ws_size,
                              hipStream_t stream) {
    const float* x  = (const float*)d_in[0];
    const void*  ei = d_in[1];
    const float* ew = (const float*)d_in[2];
    const float* W1 = (const float*)d_in[3];
    const float* b1 = (const float*)d_in[4];
    const float* W2 = (const float*)d_in[5];
    const float* b2 = (const float*)d_in[6];
    const float* W3 = (const float*)d_in[7];
    const float* b3 = (const float*)d_in[8];
    float* out = (float*)d_out;

    const int n = in_sizes[0] / 512;
    const int e = in_sizes[2];
    const int nb = (n + 127) >> 7;

    char* ws = (char*)d_ws;
    size_t off = 0;
    auto alloc = [&](size_t bytes) {
        void* p = ws + off;
        off = (off + bytes + 255) & ~(size_t)255;
        return p;
    };
    int*    flag     = (int*)   alloc(4);
    int2*   binned   = (int2*)  alloc((size_t)e * 8);   // aliased as hbuf after k_place
    __bf16* hbuf     = (__bf16*)binned;                 // n*64*2 = 12.8MB <= e*8
    int*    bkt_cnt  = (int*)   alloc((size_t)(MAXNB + 1) * 4);
    int*    bkt_offs = (int*)   alloc((size_t)(MAXNB + 1) * 4);
    int*    bkt_cur  = (int*)   alloc((size_t)(MAXNB + 1) * 4);
    int*    counts   = (int*)   alloc((size_t)n * 4);
    int*    offs     = (int*)   alloc((size_t)(n + 1) * 4);
    int*    bsum     = (int*)   alloc(512);
    int2*   csrp     = (int2*)  alloc((size_t)e * 8);
    float*  dinv     = (float*) alloc((size_t)n * 4);
    float*  pbuf     = (float*) alloc((size_t)n * 64 * 4);
    float*  h3       = (float*) alloc((size_t)n * 4);
    __bf16* Wtf      = (__bf16*)alloc((size_t)512 * 64 * 2);
    (void)ws_size; (void)n_in; (void)out_size;

    const int gb_n = (n + BLK - 1) / BLK;
    const int nb_scan = (n + 1023) / 1024;

    k_detect<<<1, 64, 0, stream>>>((const int*)ei, e, flag);

    // ---- CSR build via 2-level binning
    k_zero_i<<<(nb + BLK - 1) / BLK, BLK, 0, stream>>>(bkt_cnt, nb);
    k_binhist<<<NBLKBIN, 256, 0, stream>>>(ei, e, flag, bkt_cnt, nb);
    k_scanbkt<<<1, 256, 0, stream>>>(bkt_cnt, bkt_offs, bkt_cur, nb, e);
    k_binscatter<<<NBLKBIN, 256, 0, stream>>>(ei, ew, e, flag, bkt_cur, binned, nb);
    k_bucketcnt<<<nb, 256, 0, stream>>>(bkt_offs, binned, counts, dinv, n);
    k_scan1<<<nb_scan, 256, 0, stream>>>(counts, counts, bsum, n);
    k_scan2<<<1, 128, 0, stream>>>(bsum, nb_scan);
    k_scan3<<<gb_n, BLK, 0, stream>>>(offs, counts, bsum, n, e);
    k_place<<<nb, 256, 0, stream>>>(bkt_offs, binned, offs, dinv, csrp, n);

    // W1 -> bf16 fragment-major (64 KB, streamed)
    k_wcvt_frag<<<(4096 + BLK - 1) / BLK, BLK, 0, stream>>>(W1, Wtf);

    // ---- layer 1: 512 -> 64 (bf16 MFMA -> bf16 h; hbuf aliases binned, dead now)
    {
        k_gemm1_mfma<<<(n + 63) / 64, 256, 0, stream>>>(x, Wtf, hbuf, n);
        k_prop_bf<64><<<(n + 7) / 8, 256, 0, stream>>>(offs, csrp, hbuf, dinv, b1, pbuf, n);
    }
    // ---- layer 2: 64 -> 32 (f32 VALU, ReLU on input, bf16 out)
    {
        constexpr int ROWS = (256 / (32 / 4)) * 8;  // 256
        k_gemm<64, 32, 64, 8, true><<<(n + ROWS - 1) / ROWS, BLK, 0, stream>>>(pbuf, W2, hbuf, n);
        k_prop_bf<32><<<(n + 15) / 16, 256, 0, stream>>>(offs, csrp, hbuf, dinv, b2, pbuf, n);
    }
    // ---- layer 3: 32 -> 1 (ReLU inside lin3, all f32)
    {
        k_lin3<<<gb_n, BLK, 0, stream>>>(pbuf, W3, h3, n);
        k_prop1<<<gb_n, BLK, 0, stream>>>(offs, csrp, h3, dinv, b3, out, n);
    }
}

// Round 6
// 390.805 us; speedup vs baseline: 12.8930x; 1.2195x over previous
//
#include <hip/hip_runtime.h>

constexpr int BLK = 256;
constexpr int NBLKBIN = 512;      // blocks for binning passes
constexpr int MAXNB   = 1024;     // max buckets (supports n <= 131072)

typedef __bf16 bf16x8 __attribute__((ext_vector_type(8)));
typedef float  f32x4  __attribute__((ext_vector_type(4)));

__device__ __forceinline__ float blo(unsigned u) { return __uint_as_float(u << 16); }
__device__ __forceinline__ float bhi(unsigned u) { return __uint_as_float(u & 0xffff0000u); }

// ---------------------------------------------------------------- index width detect
__global__ void k_detect(const int* __restrict__ ei, int e, int* __restrict__ flag) {
    if (blockIdx.x == 0 && threadIdx.x == 0) {
        int is64 = 1;
        for (int i = 0; i < 16; ++i)
            if (ei[2 * i + 1] != 0) { is64 = 0; break; }
        *flag = is64;
    }
}

__device__ __forceinline__ int load_idx(const void* ei, size_t pos, int is64) {
    if (is64) return (int)((const long long*)ei)[pos];
    return ((const int*)ei)[pos];
}

__global__ void k_zero_i(int* __restrict__ p, int n) {
    long i = (long)blockIdx.x * BLK + threadIdx.x;
    if (i < n) p[i] = 0;
}

// ---------------------------------------------------------------- B1: coarse bucket histogram
__global__ __launch_bounds__(256) void k_binhist(const void* __restrict__ ei, int e,
                                                 const int* __restrict__ flag,
                                                 int* __restrict__ bucket_cnt, int nb) {
    __shared__ int hist[MAXNB];
    const int t = threadIdx.x;
    for (int b = t; b < nb; b += 256) hist[b] = 0;
    __syncthreads();
    const int is64 = *flag;
    const int chunk = (e + NBLKBIN - 1) / NBLKBIN;
    const int i0 = blockIdx.x * chunk;
    const int i1 = min(e, i0 + chunk);
    for (int i = i0 + t; i < i1; i += 256) {
        int dst = load_idx(ei, (size_t)e + i, is64);
        atomicAdd(&hist[dst >> 7], 1);
    }
    __syncthreads();
    for (int b = t; b < nb; b += 256) {
        int c = hist[b];
        if (c) atomicAdd(&bucket_cnt[b], c);
    }
}

// ---------------------------------------------------------------- B2: scan buckets
__global__ void k_scanbkt(const int* __restrict__ cnt, int* __restrict__ offs,
                          int* __restrict__ cursor, int nb, int e) {
    __shared__ int sh[256];
    const int t = threadIdx.x;
    const int base = t * 4;
    int v[4]; int s = 0;
#pragma unroll
    for (int k = 0; k < 4; ++k) {
        int i = base + k;
        v[k] = (i < nb) ? cnt[i] : 0;
        s += v[k];
    }
    sh[t] = s;
    __syncthreads();
    for (int d = 1; d < 256; d <<= 1) {
        int x = (t >= d) ? sh[t - d] : 0;
        __syncthreads();
        sh[t] += x;
        __syncthreads();
    }
    int excl = (t == 0) ? 0 : sh[t - 1];
#pragma unroll
    for (int k = 0; k < 4; ++k) {
        int i = base + k;
        if (i < nb) { offs[i] = excl; cursor[i] = excl; excl += v[k]; }
    }
    if (t == 255) offs[nb] = e;
}

// ---------------------------------------------------------------- B3: scatter into buckets
// payload: x = src | (dst&127)<<20 ; y = bits(weight)
__global__ __launch_bounds__(256) void k_binscatter(const void* __restrict__ ei,
                                                    const float* __restrict__ ew, int e,
                                                    const int* __restrict__ flag,
                                                    int* __restrict__ bucket_cursor,
                                                    int2* __restrict__ binned, int nb) {
    __shared__ int hist[MAXNB];
    const int t = threadIdx.x;
    for (int b = t; b < nb; b += 256) hist[b] = 0;
    __syncthreads();
    const int is64 = *flag;
    const int chunk = (e + NBLKBIN - 1) / NBLKBIN;
    const int i0 = blockIdx.x * chunk;
    const int i1 = min(e, i0 + chunk);
    for (int i = i0 + t; i < i1; i += 256) {
        int dst = load_idx(ei, (size_t)e + i, is64);
        atomicAdd(&hist[dst >> 7], 1);
    }
    __syncthreads();
    for (int b = t; b < nb; b += 256) {
        int c = hist[b];
        int base = 0;
        if (c) base = atomicAdd(&bucket_cursor[b], c);
        hist[b] = base;
    }
    __syncthreads();
    for (int i = i0 + t; i < i1; i += 256) {
        int dst = load_idx(ei, (size_t)e + i, is64);
        int src = load_idx(ei, (size_t)i, is64);
        float w = ew[i];
        int bin = dst >> 7;
        int pos = atomicAdd(&hist[bin], 1);
        binned[pos] = make_int2(src | ((dst & 127) << 20), __float_as_int(w));
    }
}

// ---------------------------------------------------------------- B4: per-dst counts + degree/dinv
__global__ __launch_bounds__(256) void k_bucketcnt(const int* __restrict__ bucket_offs,
                                                   const int2* __restrict__ binned,
                                                   int* __restrict__ counts,
                                                   float* __restrict__ dinv, int n) {
    __shared__ int   icnt[128];
    __shared__ float facc[128];
    const int t = threadIdx.x;
    const int k = blockIdx.x;
    if (t < 128) { icnt[t] = 0; facc[t] = 0.f; }
    __syncthreads();
    const int j0 = bucket_offs[k], j1 = bucket_offs[k + 1];
    for (int j = j0 + t; j < j1; j += 256) {
        int2 p = binned[j];
        int dl = ((unsigned)p.x) >> 20;
        atomicAdd(&icnt[dl], 1);
        atomicAdd(&facc[dl], __int_as_float(p.y));
    }
    __syncthreads();
    if (t < 128) {
        int nd = k * 128 + t;
        if (nd < n) {
            counts[nd] = icnt[t];
            dinv[nd] = rsqrtf(1.0f + facc[t]);
        }
    }
}

// ---------------------------------------------------------------- scan over nodes (counts -> offs)
__global__ void k_scan1(const int* __restrict__ in, int* __restrict__ out,
                        int* __restrict__ bsum, int n) {
    __shared__ int sh[256];
    const int t = threadIdx.x;
    const int base = blockIdx.x * 1024 + t * 4;
    int v[4];
    int s = 0;
#pragma unroll
    for (int k = 0; k < 4; ++k) {
        int i = base + k;
        v[k] = (i < n) ? in[i] : 0;
        s += v[k];
    }
    sh[t] = s;
    __syncthreads();
    for (int d = 1; d < 256; d <<= 1) {
        int x = (t >= d) ? sh[t - d] : 0;
        __syncthreads();
        sh[t] += x;
        __syncthreads();
    }
    int excl = (t == 0) ? 0 : sh[t - 1];
    if (t == 255) bsum[blockIdx.x] = sh[255];
#pragma unroll
    for (int k = 0; k < 4; ++k) {
        int i = base + k;
        if (i < n) { out[i] = excl; excl += v[k]; }
    }
}

__global__ void k_scan2(int* __restrict__ bsum, int nb) {
    __shared__ int sh[128];
    const int t = threadIdx.x;
    sh[t] = (t < nb) ? bsum[t] : 0;
    __syncthreads();
    for (int d = 1; d < 128; d <<= 1) {
        int x = (t >= d) ? sh[t - d] : 0;
        __syncthreads();
        sh[t] += x;
        __syncthreads();
    }
    if (t < nb) bsum[t] = (t == 0) ? 0 : sh[t - 1];
}

__global__ void k_scan3(int* __restrict__ offs, const int* __restrict__ scanned,
                        const int* __restrict__ bsum, int n, int e) {
    long i = (long)blockIdx.x * BLK + threadIdx.x;
    if (i < n) offs[i] = scanned[i] + bsum[i >> 10];
    if (i == 0) offs[n] = e;
}

// ---------------------------------------------------------------- B5: exact CSR placement (+ fold dinv[src])
__global__ __launch_bounds__(256) void k_place(const int* __restrict__ bucket_offs,
                                               const int2* __restrict__ binned,
                                               const int* __restrict__ offs,
                                               const float* __restrict__ dinv,
                                               int2* __restrict__ csrp, int n) {
    __shared__ int cur[128];
    const int t = threadIdx.x;
    const int k = blockIdx.x;
    if (t < 128) {
        int nd = k * 128 + t;
        cur[t] = (nd < n) ? offs[nd] : 0;
    }
    __syncthreads();
    const int j0 = bucket_offs[k], j1 = bucket_offs[k + 1];
    for (int j = j0 + t; j < j1; j += 256) {
        int2 p = binned[j];
        int dl  = ((unsigned)p.x) >> 20;
        int src = p.x & 0xFFFFF;
        int pos = atomicAdd(&cur[dl], 1);
        float w2 = __int_as_float(p.y) * dinv[src];
        csrp[pos] = make_int2(src, __float_as_int(w2));
    }
}

// ---------------------------------------------------------------- W1 -> bf16 fragment-major
// Wtf[k0c][t][lane][j] ; col = t*16 + (lane&15), k = k0c*32 + (lane>>4)*8 + j
__global__ void k_wcvt_frag(const float* __restrict__ W, __bf16* __restrict__ Wtf) {
    int i = blockIdx.x * BLK + threadIdx.x;       // over 16*4*64 = 4096
    if (i >= 4096) return;
    int lane = i & 63;
    int t    = (i >> 6) & 3;
    int k0c  = i >> 8;
    int col  = t * 16 + (lane & 15);
    int kbase = k0c * 32 + (lane >> 4) * 8;
    bf16x8 v;
#pragma unroll
    for (int j = 0; j < 8; ++j) v[j] = (__bf16)W[(size_t)(kbase + j) * 64 + col];
    *(bf16x8*)(Wtf + (size_t)i * 8) = v;
}

// W2 [64][32] -> fragment-major: i = (chunk*2+t)*64+lane over 256
__global__ void k_wcvt_frag2(const float* __restrict__ W, __bf16* __restrict__ Wtf2) {
    int i = threadIdx.x;
    int lane = i & 63;
    int ct   = i >> 6;          // chunk*2 + t
    int t = ct & 1, chunk = ct >> 1;
    int col  = t * 16 + (lane & 15);
    int kbase = chunk * 32 + (lane >> 4) * 8;
    bf16x8 v;
#pragma unroll
    for (int j = 0; j < 8; ++j) v[j] = (__bf16)W[(size_t)(kbase + j) * 32 + col];
    *(bf16x8*)(Wtf2 + (size_t)i * 8) = v;
}

// ---------------------------------------------------------------- GEMM1: bf16 MFMA, pipelined A loads
__global__ __launch_bounds__(256) void k_gemm1_mfma(const float* __restrict__ X,
                                                    const __bf16* __restrict__ Wtf,
                                                    __bf16* __restrict__ H, int nrows) {
    const int wave = threadIdx.x >> 6;
    const int lane = threadIdx.x & 63;
    const int l15  = lane & 15;
    const int lq   = lane >> 4;
    const long rbase = (long)blockIdx.x * 64 + wave * 16;

    long arow = rbase + l15;
    if (arow >= nrows) arow = nrows - 1;
    const float4* xr4 = (const float4*)(X + (size_t)arow * 512) + lq * 2;  // chunk stride = 8 float4

    f32x4 acc[4] = {{0.f,0.f,0.f,0.f},{0.f,0.f,0.f,0.f},{0.f,0.f,0.f,0.f},{0.f,0.f,0.f,0.f}};

    // software pipeline, depth 4 (fully unrolled -> static reg indices)
    float4 pa[4][2];
#pragma unroll
    for (int p = 0; p < 4; ++p) { pa[p][0] = xr4[p * 8]; pa[p][1] = xr4[p * 8 + 1]; }

#pragma unroll
    for (int k0c = 0; k0c < 16; ++k0c) {
        const int s = k0c & 3;
        float4 a0 = pa[s][0];
        float4 a1 = pa[s][1];
        if (k0c + 4 < 16) {
            pa[s][0] = xr4[(k0c + 4) * 8];
            pa[s][1] = xr4[(k0c + 4) * 8 + 1];
        }
        bf16x8 af;
        af[0] = (__bf16)a0.x; af[1] = (__bf16)a0.y; af[2] = (__bf16)a0.z; af[3] = (__bf16)a0.w;
        af[4] = (__bf16)a1.x; af[5] = (__bf16)a1.y; af[6] = (__bf16)a1.z; af[7] = (__bf16)a1.w;
#pragma unroll
        for (int t = 0; t < 4; ++t) {
            bf16x8 bf_ = *(const bf16x8*)(Wtf + ((size_t)(k0c * 4 + t) * 64 + lane) * 8);
            acc[t] = __builtin_amdgcn_mfma_f32_16x16x32_bf16(af, bf_, acc[t], 0, 0, 0);
        }
    }
    // C layout: col = l15, row = lq*4 + reg
#pragma unroll
    for (int t = 0; t < 4; ++t) {
#pragma unroll
        for (int r = 0; r < 4; ++r) {
            long row = rbase + lq * 4 + r;
            if (row < nrows) H[(size_t)row * 64 + t * 16 + l15] = (__bf16)acc[t][r];
        }
    }
}

// ---------------------------------------------------------------- GEMM2: 64 -> 32 bf16 MFMA
__global__ __launch_bounds__(256) void k_gemm2_mfma(const __bf16* __restrict__ A,
                                                    const __bf16* __restrict__ Wtf2,
                                                    __bf16* __restrict__ H, int nrows) {
    const int wave = threadIdx.x >> 6;
    const int lane = threadIdx.x & 63;
    const int l15  = lane & 15;
    const int lq   = lane >> 4;
    const long rbase = (long)blockIdx.x * 64 + wave * 16;

    long arow = rbase + l15;
    if (arow >= nrows) arow = nrows - 1;

    f32x4 acc[2] = {{0.f,0.f,0.f,0.f},{0.f,0.f,0.f,0.f}};
#pragma unroll
    for (int c = 0; c < 2; ++c) {
        bf16x8 af = *(const bf16x8*)(A + (size_t)arow * 64 + c * 32 + lq * 8);
#pragma unroll
        for (int t = 0; t < 2; ++t) {
            bf16x8 bf_ = *(const bf16x8*)(Wtf2 + ((size_t)(c * 2 + t) * 64 + lane) * 8);
            acc[t] = __builtin_amdgcn_mfma_f32_16x16x32_bf16(af, bf_, acc[t], 0, 0, 0);
        }
    }
#pragma unroll
    for (int t = 0; t < 2; ++t) {
#pragma unroll
        for (int r = 0; r < 4; ++r) {
            long row = rbase + lq * 4 + r;
            if (row < nrows) H[(size_t)row * 32 + t * 16 + l15] = (__bf16)acc[t][r];
        }
    }
}

// ---------------------------------------------------------------- propagation (CSR gather, bf16 h)
// lane owns 2 channels (one u32 load); K/2 lanes per node
// RELU applied to output; OBF16 selects bf16-packed vs f32 output
template <int K, bool RELU, bool OBF16>
__global__ __launch_bounds__(256) void k_prop_bf(const int* __restrict__ offs,
                                                 const int2* __restrict__ csrp,
                                                 const __bf16* __restrict__ hb,
                                                 const float* __restrict__ dinv,
                                                 const float* __restrict__ bias,
                                                 void* __restrict__ outv, int n) {
    constexpr int SUB = K / 2;           // lanes per node
    constexpr int NPW = 64 / SUB;        // nodes per wave
    constexpr int NPB = 4 * NPW;         // nodes per block
    const int t    = threadIdx.x;
    const int lane = t & 63;
    const int wave = t >> 6;
    const int chp  = lane & (SUB - 1);   // channel pair index
    const int sub  = lane / SUB;
    const long nd  = (long)blockIdx.x * NPB + wave * NPW + sub;
    if (nd >= n) return;

    const unsigned short* h = (const unsigned short*)hb;
    const int j0 = offs[nd], j1 = offs[nd + 1];
    float a0 = 0.f, a1 = 0.f;
    int j = j0;
    for (; j + 3 < j1; j += 4) {
        int2 p0 = csrp[j];
        int2 p1 = csrp[j + 1];
        int2 p2 = csrp[j + 2];
        int2 p3 = csrp[j + 3];
        unsigned u0 = *(const unsigned*)(h + (size_t)p0.x * K + 2 * chp);
        unsigned u1 = *(const unsigned*)(h + (size_t)p1.x * K + 2 * chp);
        unsigned u2 = *(const unsigned*)(h + (size_t)p2.x * K + 2 * chp);
        unsigned u3 = *(const unsigned*)(h + (size_t)p3.x * K + 2 * chp);
        float w0 = __int_as_float(p0.y), w1 = __int_as_float(p1.y);
        float w2 = __int_as_float(p2.y), w3 = __int_as_float(p3.y);
        a0 = fmaf(w0, blo(u0), a0); a1 = fmaf(w0, bhi(u0), a1);
        a0 = fmaf(w1, blo(u1), a0); a1 = fmaf(w1, bhi(u1), a1);
        a0 = fmaf(w2, blo(u2), a0); a1 = fmaf(w2, bhi(u2), a1);
        a0 = fmaf(w3, blo(u3), a0); a1 = fmaf(w3, bhi(u3), a1);
    }
    for (; j < j1; ++j) {
        int2 p0 = csrp[j];
        unsigned u0 = *(const unsigned*)(h + (size_t)p0.x * K + 2 * chp);
        float w0 = __int_as_float(p0.y);
        a0 = fmaf(w0, blo(u0), a0);
        a1 = fmaf(w0, bhi(u0), a1);
    }
    const float di = dinv[nd];
    const float s  = di * di;
    unsigned us = *(const unsigned*)(h + (size_t)nd * K + 2 * chp);
    float2 bv = *(const float2*)(bias + 2 * chp);
    float o0 = fmaf(di, a0, fmaf(s, blo(us), bv.x));
    float o1 = fmaf(di, a1, fmaf(s, bhi(us), bv.y));
    if (RELU) { o0 = fmaxf(o0, 0.f); o1 = fmaxf(o1, 0.f); }
    if (OBF16) {
        unsigned short s0 = __builtin_bit_cast(unsigned short, (__bf16)o0);
        unsigned short s1 = __builtin_bit_cast(unsigned short, (__bf16)o1);
        ((unsigned*)outv)[(size_t)nd * (K / 2) + chp] = (unsigned)s0 | ((unsigned)s1 << 16);
    } else {
        *(float2*)((float*)outv + (size_t)nd * K + 2 * chp) = make_float2(o0, o1);
    }
}

// ---------------------------------------------------------------- layer 3 linear (32 -> 1, f32 in, no relu)
__global__ void k_lin3(const float* __restrict__ X, const float* __restrict__ W3,
                       float* __restrict__ h3, int n) {
    long i = (long)blockIdx.x * BLK + threadIdx.x;
    if (i >= n) return;
    const float4* xr = (const float4*)(X + (size_t)i * 32);
    float acc = 0.f;
#pragma unroll
    for (int c = 0; c < 8; ++c) {
        float4 xv = xr[c];
        float4 wv = ((const float4*)W3)[c];
        acc = fmaf(xv.x, wv.x, acc);
        acc = fmaf(xv.y, wv.y, acc);
        acc = fmaf(xv.z, wv.z, acc);
        acc = fmaf(xv.w, wv.w, acc);
    }
    h3[i] = acc;
}

// output prop: K=1, f32 h3 (one lane per node)
__global__ __launch_bounds__(256) void k_prop1(const int* __restrict__ offs,
                                               const int2* __restrict__ csrp,
                                               const float* __restrict__ h,
                                               const float* __restrict__ dinv,
                                               const float* __restrict__ bias,
                                               float* __restrict__ out, int n) {
    long nd = (long)blockIdx.x * BLK + threadIdx.x;
    if (nd >= n) return;
    const int j0 = offs[nd], j1 = offs[nd + 1];
    float acc = 0.f;
    int j = j0;
    for (; j + 3 < j1; j += 4) {
        int2 p0 = csrp[j];
        int2 p1 = csrp[j + 1];
        int2 p2 = csrp[j + 2];
        int2 p3 = csrp[j + 3];
        acc = fmaf(__int_as_float(p0.y), h[p0.x], acc);
        acc = fmaf(__int_as_float(p1.y), h[p1.x], acc);
        acc = fmaf(__int_as_float(p2.y), h[p2.x], acc);
        acc = fmaf(__int_as_float(p3.y), h[p3.x], acc);
    }
    for (; j < j1; ++j) {
        int2 p0 = csrp[j];
        acc = fmaf(__int_as_float(p0.y), h[p0.x], acc);
    }
    const float di = dinv[nd];
    out[nd] = fmaf(di, acc, fmaf(di * di, h[nd], bias[0]));
}

// ---------------------------------------------------------------- launch
extern "C" void kernel_launch(void* const* d_in, const int* in_sizes, int n_in,
                              void* d_out, int out_size, void* d_ws, size_t ws_size,
                              hipStream_t stream) {
    const float* x  = (const float*)d_in[0];
    const void*  ei = d_in[1];
    const float* ew = (const float*)d_in[2];
    const float* W1 = (const float*)d_in[3];
    const float* b1 = (const float*)d_in[4];
    const float* W2 = (const float*)d_in[5];
    const float* b2 = (const float*)d_in[6];
    const float* W3 = (const float*)d_in[7];
    const float* b3 = (const float*)d_in[8];
    float* out = (float*)d_out;

    const int n = in_sizes[0] / 512;
    const int e = in_sizes[2];
    const int nb = (n + 127) >> 7;

    char* ws = (char*)d_ws;
    size_t off = 0;
    auto alloc = [&](size_t bytes) {
        void* p = ws + off;
        off = (off + bytes + 255) & ~(size_t)255;
        return p;
    };
    int*    flag     = (int*)   alloc(4);
    int2*   binned   = (int2*)  alloc((size_t)e * 8);   // aliased as hbuf1 after k_place
    __bf16* hbuf1    = (__bf16*)binned;                 // n*64*2 = 12.8MB <= e*8
    int*    bkt_cnt  = (int*)   alloc((size_t)(MAXNB + 1) * 4);
    int*    bkt_offs = (int*)   alloc((size_t)(MAXNB + 1) * 4);
    int*    bkt_cur  = (int*)   alloc((size_t)(MAXNB + 1) * 4);
    int*    counts   = (int*)   alloc((size_t)n * 4);
    int*    offs     = (int*)   alloc((size_t)(n + 1) * 4);
    int*    bsum     = (int*)   alloc(512);
    int2*   csrp     = (int2*)  alloc((size_t)e * 8);
    float*  dinv     = (float*) alloc((size_t)n * 4);
    __bf16* pb64     = (__bf16*)alloc((size_t)n * 64 * 2);  // relu'd prop1 out (layer2 in)
    __bf16* hbuf2    = (__bf16*)alloc((size_t)n * 32 * 2);  // gemm2 out
    float*  pf32     = (float*) alloc((size_t)n * 32 * 4);  // relu'd prop2 out (layer3 in)
    float*  h3       = (float*) alloc((size_t)n * 4);
    __bf16* Wtf      = (__bf16*)alloc((size_t)512 * 64 * 2);
    __bf16* Wtf2     = (__bf16*)alloc((size_t)64 * 32 * 2);
    (void)ws_size; (void)n_in; (void)out_size;

    const int gb_n = (n + BLK - 1) / BLK;
    const int nb_scan = (n + 1023) / 1024;

    k_detect<<<1, 64, 0, stream>>>((const int*)ei, e, flag);

    // ---- CSR build via 2-level binning
    k_zero_i<<<(nb + BLK - 1) / BLK, BLK, 0, stream>>>(bkt_cnt, nb);
    k_binhist<<<NBLKBIN, 256, 0, stream>>>(ei, e, flag, bkt_cnt, nb);
    k_scanbkt<<<1, 256, 0, stream>>>(bkt_cnt, bkt_offs, bkt_cur, nb, e);
    k_binscatter<<<NBLKBIN, 256, 0, stream>>>(ei, ew, e, flag, bkt_cur, binned, nb);
    k_bucketcnt<<<nb, 256, 0, stream>>>(bkt_offs, binned, counts, dinv, n);
    k_scan1<<<nb_scan, 256, 0, stream>>>(counts, counts, bsum, n);
    k_scan2<<<1, 128, 0, stream>>>(bsum, nb_scan);
    k_scan3<<<gb_n, BLK, 0, stream>>>(offs, counts, bsum, n, e);
    k_place<<<nb, 256, 0, stream>>>(bkt_offs, binned, offs, dinv, csrp, n);

    // weights -> bf16 fragment-major
    k_wcvt_frag<<<(4096 + BLK - 1) / BLK, BLK, 0, stream>>>(W1, Wtf);
    k_wcvt_frag2<<<1, 256, 0, stream>>>(W2, Wtf2);

    // ---- layer 1: 512 -> 64 (bf16 MFMA; hbuf1 aliases binned, dead after place)
    k_gemm1_mfma<<<(n + 63) / 64, 256, 0, stream>>>(x, Wtf, hbuf1, n);
    k_prop_bf<64, true, true><<<(n + 7) / 8, 256, 0, stream>>>(offs, csrp, hbuf1, dinv, b1, pb64, n);

    // ---- layer 2: 64 -> 32 (bf16 MFMA)
    k_gemm2_mfma<<<(n + 63) / 64, 256, 0, stream>>>(pb64, Wtf2, hbuf2, n);
    k_prop_bf<32, true, false><<<(n + 15) / 16, 256, 0, stream>>>(offs, csrp, hbuf2, dinv, b2, pf32, n);

    // ---- layer 3: 32 -> 1 (f32)
    k_lin3<<<gb_n, BLK, 0, stream>>>(pf32, W3, h3, n);
    k_prop1<<<gb_n, BLK, 0, stream>>>(offs, csrp, h3, dinv, b3, out, n);
}